// Round 1
// baseline (777.793 us; speedup 1.0000x reference)
//
#include <hip/hip_runtime.h>

typedef unsigned short u16;
typedef unsigned int u32;
typedef unsigned long long u64;
typedef __attribute__((ext_vector_type(8))) short bf16x8;
typedef __attribute__((ext_vector_type(4))) float f32x4;

__device__ __forceinline__ float b2f(u16 v) {
  union { u32 u; float f; } c; c.u = ((u32)v) << 16; return c.f;
}
__device__ __forceinline__ u16 f2b(float f) {
  union { float f; u32 u; } c; c.f = f;
  return (u16)((c.u + 0x7fffu + ((c.u >> 16) & 1u)) >> 16);
}

// async global->LDS, 16B per lane (global_load_lds_dwordx4).
__device__ __forceinline__ void g2l16(const u16* g, u16* l) {
  __builtin_amdgcn_global_load_lds(
      (const __attribute__((address_space(1))) u32*)g,
      (__attribute__((address_space(3))) u32*)l,
      16, 0, 0);
}

// tanh-form GELU: gelu(x) = x * sigmoid(1.5957691f * x * (1 + 0.044715 x^2)).
// Max |delta| vs exact erf-GELU ~3e-4; hw v_exp_f32 + v_rcp_f32, ~9 VALU ops
// vs ~60+ for erff.
__device__ __forceinline__ float gelu_fast(float x) {
  float z2 = -1.5957691216057308f * x * (1.0f + 0.044715f * x * x);  // -2z
  z2 = fminf(fmaxf(z2, -30.f), 30.f);
  float t = __expf(z2);
  return x * __builtin_amdgcn_rcpf(1.0f + t);
}

// ---------------- LDS-tiled weight repacks (fp32 in -> bf16 out) -------------
__global__ __launch_bounds__(256)
void repack_qkv_tiled(const float* __restrict__ Wq, const float* __restrict__ Wk,
                      const float* __restrict__ Wv, u16* __restrict__ WT) {
  __shared__ u16 tile[64][65];
  const int sh = blockIdx.y, sel = sh >> 4, h = sh & 15;
  const float* W = (sel == 0) ? Wq : ((sel == 1) ? Wk : Wv);
  const int k0 = blockIdx.x * 64;
  {
    const int d = threadIdx.x & 63, r = threadIdx.x >> 6;
    #pragma unroll
    for (int i = 0; i < 16; ++i) {
      int k = r * 16 + i;
      tile[k][d] = f2b(W[(size_t)h * 65536 + (size_t)(k0 + k) * 64 + d]);
    }
  }
  __syncthreads();
  {
    const int k = threadIdx.x & 63, dd = threadIdx.x >> 6;
    #pragma unroll
    for (int i = 0; i < 16; ++i) {
      int d2 = dd * 16 + i;
      WT[((size_t)sel * 1024 + h * 64 + d2) * 1024 + k0 + k] = tile[k][d2];
    }
  }
}

__global__ __launch_bounds__(256)
void transpose_tiled(const float* __restrict__ W, u16* __restrict__ WT,
                     int N, int K) {
  __shared__ u16 tile[32][33];
  const int bx = blockIdx.x * 32;   // n
  const int by = blockIdx.y * 32;   // k
  const int tx = threadIdx.x & 31, ty = threadIdx.x >> 5;
  #pragma unroll
  for (int i = 0; i < 4; ++i) {
    int k = ty + i * 8;
    tile[k][tx] = f2b(W[(size_t)(by + k) * N + bx + tx]);
  }
  __syncthreads();
  #pragma unroll
  for (int i = 0; i < 4; ++i) {
    int n = ty + i * 8;
    WT[(size_t)(bx + n) * K + by + tx] = tile[tx][n];
  }
}

// ---------------- LayerNorm (C=1024, EPS=1e-3), bf16 out ----------------
__global__ __launch_bounds__(256)
void ln_f32_kernel(const float* __restrict__ X, const float* __restrict__ G,
                   const float* __restrict__ Bt, u16* __restrict__ O) {
  const int row = blockIdx.x;
  const int tid = threadIdx.x;
  const float* xr = X + (size_t)row * 1024;
  float4 xv = *(const float4*)(xr + tid * 4);
  float v0 = xv.x, v1 = xv.y, v2 = xv.z, v3 = xv.w;
  float s = v0 + v1 + v2 + v3;
  float q = v0 * v0 + v1 * v1 + v2 * v2 + v3 * v3;
  #pragma unroll
  for (int off = 32; off > 0; off >>= 1) {
    s += __shfl_down(s, off);
    q += __shfl_down(q, off);
  }
  __shared__ float red[8];
  int wave = tid >> 6, lane = tid & 63;
  if (lane == 0) { red[wave] = s; red[4 + wave] = q; }
  __syncthreads();
  s = red[0] + red[1] + red[2] + red[3];
  q = red[4] + red[5] + red[6] + red[7];
  float mean = s * (1.f / 1024.f);
  float var = q * (1.f / 1024.f) - mean * mean;
  float rstd = rsqrtf(var + 1e-3f);
  float4 gv = *(const float4*)(G + tid * 4);
  float4 bv = *(const float4*)(Bt + tid * 4);
  ushort4 ov;
  ov.x = f2b((v0 - mean) * rstd * gv.x + bv.x);
  ov.y = f2b((v1 - mean) * rstd * gv.y + bv.y);
  ov.z = f2b((v2 - mean) * rstd * gv.z + bv.z);
  ov.w = f2b((v3 - mean) * rstd * gv.w + bv.w);
  *(ushort4*)(O + (size_t)row * 1024 + tid * 4) = ov;
}

__global__ __launch_bounds__(256)
void ln_bf16_kernel(const u16* __restrict__ X, const float* __restrict__ G,
                    const float* __restrict__ Bt, u16* __restrict__ O) {
  const int row = blockIdx.x;
  const int tid = threadIdx.x;
  const u16* xr = X + (size_t)row * 1024;
  ushort4 xv = *(const ushort4*)(xr + tid * 4);
  float v0 = b2f(xv.x), v1 = b2f(xv.y), v2 = b2f(xv.z), v3 = b2f(xv.w);
  float s = v0 + v1 + v2 + v3;
  float q = v0 * v0 + v1 * v1 + v2 * v2 + v3 * v3;
  #pragma unroll
  for (int off = 32; off > 0; off >>= 1) {
    s += __shfl_down(s, off);
    q += __shfl_down(q, off);
  }
  __shared__ float red[8];
  int wave = tid >> 6, lane = tid & 63;
  if (lane == 0) { red[wave] = s; red[4 + wave] = q; }
  __syncthreads();
  s = red[0] + red[1] + red[2] + red[3];
  q = red[4] + red[5] + red[6] + red[7];
  float mean = s * (1.f / 1024.f);
  float var = q * (1.f / 1024.f) - mean * mean;
  float rstd = rsqrtf(var + 1e-3f);
  float4 gv = *(const float4*)(G + tid * 4);
  float4 bv = *(const float4*)(Bt + tid * 4);
  ushort4 ov;
  ov.x = f2b((v0 - mean) * rstd * gv.x + bv.x);
  ov.y = f2b((v1 - mean) * rstd * gv.y + bv.y);
  ov.z = f2b((v2 - mean) * rstd * gv.z + bv.z);
  ov.w = f2b((v3 - mean) * rstd * gv.w + bv.w);
  *(ushort4*)(O + (size_t)row * 1024 + tid * 4) = ov;
}

// ---------------- NT GEMM, 256x256 tile, 8-phase counted-vmcnt schedule ------
// A[M,K] * BT[N,K]^T, bf16 in, fp32 acc. 512 threads = 8 waves (2M x 4N),
// per-wave 128x64 output (acc[8][4]). BK=64, double-buffered LDS 128 KiB:
//   A: smem[0 .. 32768)  = [2][256][64] u16, B: smem[32768 .. 65536).
// Row = 128B; 16B k-chunk slot XOR-swizzled with (row&7)  (T2, verified).
// Per K-tile: 4 phases {ds_read subtile | prefetch issue | s_barrier |
// setprio(1) 16 MFMA setprio(0) | s_barrier}; raw s_barrier (no vmcnt drain).
// Counted vmcnt(6) at tile boundary only: 3 half-tiles (6 loads) stay in
// flight across barriers (T3+T4). Buffer p is only re-written after the
// end-of-tile barrier that releases it; every wave does the same counted
// wait before the same barrier, so post-barrier all waves' LDS data is valid.
// EPI 0: qkv 3-part bias; 1: bias+residual (bf16 out); 2: bias+GELU;
// 3: bias+residual (fp32 out).
#define MFMA16 __builtin_amdgcn_mfma_f32_16x16x32_bf16

template <int EPI>
__global__ __launch_bounds__(512, 2)
void gemm_nt8(const u16* __restrict__ A, const u16* __restrict__ BT,
              void* __restrict__ Cout,
              const float* __restrict__ bias0, const float* __restrict__ bias1,
              const float* __restrict__ bias2, const u16* __restrict__ resid,
              int M, int N, int K) {
  extern __shared__ u16 smem[];   // 128 KiB dynamic
  const int tid = threadIdx.x;
  const int m0 = blockIdx.y * 256;
  const int n0 = blockIdx.x * 256;
  const int wave = tid >> 6, lane = tid & 63;
  const int wm = wave >> 2, wn = wave & 3;
  const int quad = lane >> 4, l16 = lane & 15;
  const int nt = K >> 6;

  // staging: thread tid -> row tid>>3 (of a 64-row slab), slot tid&7.
  // stored slot s of row r holds logical k-chunk s ^ (r&7).
  const int rowS = tid >> 3;
  const int swz = ((tid & 7) ^ (rowS & 7)) * 8;
  const u16* aG = A + (size_t)(m0 + rowS) * K + swz;
  const u16* bG = BT + (size_t)(n0 + rowS) * K + swz;
  const size_t r64 = (size_t)64 * K;
  u16* aL = &smem[(u32)tid * 8];
  u16* bL = &smem[32768 + (u32)tid * 8];

  // stage half h (128 rows) of K-tile kt into buffer buf (2 loads/thread)
  auto stage_half = [&](const u16* gbase, u16* lbase, int buf, int kt, int h) {
    const u16* s = gbase + (size_t)(h * 128) * K + kt * 64;
    u16* d = lbase + buf * 16384 + h * 8192;
    g2l16(s, d);
    g2l16(s + r64, d + 4096);
  };

  f32x4 acc[8][4];
  #pragma unroll
  for (int i = 0; i < 8; ++i)
    #pragma unroll
    for (int j = 0; j < 4; ++j) acc[i][j] = (f32x4){0.f, 0.f, 0.f, 0.f};

  // prologue: tile0 fully (8 loads) + tile1 Ah0,Ah1,Bh0 (6 loads)
  stage_half(aG, aL, 0, 0, 0); stage_half(aG, aL, 0, 0, 1);
  stage_half(bG, bL, 0, 0, 0); stage_half(bG, bL, 0, 0, 1);
  if (nt > 1) {
    stage_half(aG, aL, 1, 1, 0); stage_half(aG, aL, 1, 1, 1);
    stage_half(bG, bL, 1, 1, 0);
    asm volatile("s_waitcnt vmcnt(6)" ::: "memory");
  } else {
    asm volatile("s_waitcnt vmcnt(0)" ::: "memory");
  }
  __builtin_amdgcn_s_barrier();

  // fragment addressing: row = (wm*128|wn*64) + f*16 + l16, chunk ks*4+quad,
  // slot = chunk ^ (l16&7)  (row base multiples of 8 keep the key = l16&7)
  const int s0 = (quad ^ (l16 & 7)) * 8;
  const int s1 = ((4 + quad) ^ (l16 & 7)) * 8;
  const u32 aRow = (u32)(wm * 128 + l16) * 64;
  const u32 bRow = 32768u + (u32)(wn * 64 + l16) * 64;

  bf16x8 aF[4][2], bF[4][2];

  for (int t = 0; t < nt; ++t) {
    const int p = t & 1;
    const u16* aP = &smem[aRow + p * 16384];
    const u16* bP = &smem[bRow + p * 16384];

    // ---- phase 0: read A i0-3 + B j0-1; issue Bh1(t+1); MFMA (i0-3)x(j0-1)
    #pragma unroll
    for (int i = 0; i < 4; ++i) {
      aF[i][0] = *(const bf16x8*)(aP + i * 1024 + s0);
      aF[i][1] = *(const bf16x8*)(aP + i * 1024 + s1);
    }
    #pragma unroll
    for (int j = 0; j < 2; ++j) {
      bF[j][0] = *(const bf16x8*)(bP + j * 1024 + s0);
      bF[j][1] = *(const bf16x8*)(bP + j * 1024 + s1);
    }
    if (t + 1 < nt) stage_half(bG, bL, p ^ 1, t + 1, 1);
    __builtin_amdgcn_s_barrier();
    __builtin_amdgcn_s_setprio(1);
    #pragma unroll
    for (int i = 0; i < 4; ++i)
      #pragma unroll
      for (int j = 0; j < 2; ++j) {
        acc[i][j] = MFMA16(aF[i][0], bF[j][0], acc[i][j], 0, 0, 0);
        acc[i][j] = MFMA16(aF[i][1], bF[j][1], acc[i][j], 0, 0, 0);
      }
    __builtin_amdgcn_s_setprio(0);
    __builtin_amdgcn_s_barrier();

    // ---- phase 1: read B j2-3; MFMA (i0-3)x(j2-3)
    #pragma unroll
    for (int j = 2; j < 4; ++j) {
      bF[j][0] = *(const bf16x8*)(bP + j * 1024 + s0);
      bF[j][1] = *(const bf16x8*)(bP + j * 1024 + s1);
    }
    __builtin_amdgcn_s_barrier();
    __builtin_amdgcn_s_setprio(1);
    #pragma unroll
    for (int i = 0; i < 4; ++i)
      #pragma unroll
      for (int j = 2; j < 4; ++j) {
        acc[i][j] = MFMA16(aF[i][0], bF[j][0], acc[i][j], 0, 0, 0);
        acc[i][j] = MFMA16(aF[i][1], bF[j][1], acc[i][j], 0, 0, 0);
      }
    __builtin_amdgcn_s_setprio(0);
    __builtin_amdgcn_s_barrier();

    // ---- phase 2: read A i4-7; MFMA (i4-7)x(j0-1)
    #pragma unroll
    for (int i = 0; i < 4; ++i) {
      aF[i][0] = *(const bf16x8*)(aP + (i + 4) * 1024 + s0);
      aF[i][1] = *(const bf16x8*)(aP + (i + 4) * 1024 + s1);
    }
    __builtin_amdgcn_s_barrier();
    __builtin_amdgcn_s_setprio(1);
    #pragma unroll
    for (int i = 0; i < 4; ++i)
      #pragma unroll
      for (int j = 0; j < 2; ++j) {
        acc[i + 4][j] = MFMA16(aF[i][0], bF[j][0], acc[i + 4][j], 0, 0, 0);
        acc[i + 4][j] = MFMA16(aF[i][1], bF[j][1], acc[i + 4][j], 0, 0, 0);
      }
    // ---- phase 3 (no reads): MFMA (i4-7)x(j2-3)
    #pragma unroll
    for (int i = 0; i < 4; ++i)
      #pragma unroll
      for (int j = 2; j < 4; ++j) {
        acc[i + 4][j] = MFMA16(aF[i][0], bF[j][0], acc[i + 4][j], 0, 0, 0);
        acc[i + 4][j] = MFMA16(aF[i][1], bF[j][1], acc[i + 4][j], 0, 0, 0);
      }
    __builtin_amdgcn_s_setprio(0);
    __builtin_amdgcn_s_barrier();          // end-of-tile: releases buffer p

    // ---- boundary: issue Ah0,Ah1,Bh0 of t+2 into p; counted wait for t+1
    if (t + 2 < nt) {
      stage_half(aG, aL, p, t + 2, 0);
      stage_half(aG, aL, p, t + 2, 1);
      stage_half(bG, bL, p, t + 2, 0);
      asm volatile("s_waitcnt vmcnt(6)" ::: "memory");
      __builtin_amdgcn_s_barrier();
    } else if (t + 1 < nt) {
      asm volatile("s_waitcnt vmcnt(0)" ::: "memory");   // epilogue drain
      __builtin_amdgcn_s_barrier();
    }
  }

  // ---- epilogue: 4 groups of 64 rows x 256 cols staged through LDS
  // (16B-chunk XOR swizzle), then coalesced 16B stores.
  // C/D frag layout: col = l16, row = quad*4 + reg (m89).
  #pragma unroll 1
  for (int g = 0; g < 4; ++g) {
    if (wm == (g >> 1)) {
      #pragma unroll
      for (int ii = 0; ii < 4; ++ii) {
        const int fsw = (ii * 4 + quad) & 7;           // (lrow>>2)&7
        #pragma unroll
        for (int j = 0; j < 4; ++j) {
          const int chunk = wn * 8 + j * 2 + (l16 >> 3);
          const int base = ((chunk ^ fsw) * 8) + (l16 & 7);
          #pragma unroll
          for (int rr = 0; rr < 4; ++rr) {
            const int lrow = ii * 16 + quad * 4 + rr;
            smem[lrow * 256 + base] = f2b(acc[(g & 1) * 4 + ii][j][rr]);
          }
        }
      }
    }
    __syncthreads();
    #pragma unroll
    for (int s = 0; s < 4; ++s) {
      const int lrow = s * 16 + (tid >> 5);
      const int chunk = tid & 31;
      const int fsw = (lrow >> 2) & 7;
      bf16x8 cv = *(const bf16x8*)&smem[lrow * 256 + (chunk ^ fsw) * 8];
      const int gr = m0 + g * 64 + lrow;
      const int gc = n0 + chunk * 8;
      const float* bp_ = bias0;
      int cb = gc;
      if (EPI == 0) {
        const int selb = gc >> 10;
        bp_ = (selb == 0) ? bias0 : ((selb == 1) ? bias1 : bias2);
        cb = gc & 1023;
      }
      float4 bv0 = *(const float4*)(bp_ + cb);
      float4 bv1 = *(const float4*)(bp_ + cb + 4);
      float vv[8];
      #pragma unroll
      for (int e = 0; e < 8; ++e) {
        float be = (e < 4) ? ((const float*)&bv0)[e] : ((const float*)&bv1)[e - 4];
        vv[e] = b2f(((const u16*)&cv)[e]) + be;
      }
      if (EPI == 2) {
        #pragma unroll
        for (int e = 0; e < 8; ++e) vv[e] = gelu_fast(vv[e]);
      }
      if (EPI == 1 || EPI == 3) {
        bf16x8 rv = *(const bf16x8*)(resid + (size_t)gr * N + gc);
        #pragma unroll
        for (int e = 0; e < 8; ++e) vv[e] += b2f(((const u16*)&rv)[e]);
      }
      if (EPI == 3) {
        float4 o0 = {vv[0], vv[1], vv[2], vv[3]};
        float4 o1 = {vv[4], vv[5], vv[6], vv[7]};
        float* op = (float*)Cout + (size_t)gr * N + gc;
        *(float4*)op = o0;
        *(float4*)(op + 4) = o1;
      } else {
        bf16x8 ov;
        #pragma unroll
        for (int e = 0; e < 8; ++e) ((u16*)&ov)[e] = f2b(vv[e]);
        *(bf16x8*)((u16*)Cout + (size_t)gr * N + gc) = ov;
      }
    }
    __syncthreads();   // group g reads done before g+1 overwrites
  }
}

// ---------------- attention (no softmax!): M = scale * K^T V per (b,h) -------
__global__ __launch_bounds__(256)
void attn_m_kernel(const u16* __restrict__ qkv, float* __restrict__ Mbuf) {
  const int bh = blockIdx.x;
  const int b = bh >> 4, h = bh & 15;
  const u16* Kp = qkv + (size_t)b * 1024 * 3072 + 1024 + h * 64;
  const u16* Vp = Kp + 1024;
  __shared__ __align__(16) float Ks[64 * 64];
  __shared__ __align__(16) float Vs[64 * 64];
  const int tid = threadIdx.x;
  const int d1 = tid & 63, d2b = (tid >> 6) * 16;
  const int lr = tid >> 3, lc = (tid & 7) * 8;
  float acc[16];
  #pragma unroll
  for (int j = 0; j < 16; ++j) acc[j] = 0.f;
  for (int t0 = 0; t0 < 1024; t0 += 64) {
    __syncthreads();
    #pragma unroll
    for (int it = 0; it < 2; ++it) {
      int r = it * 32 + lr;
      const u16* ks = Kp + (size_t)(t0 + r) * 3072 + lc;
      const u16* vs = Vp + (size_t)(t0 + r) * 3072 + lc;
      ushort4 a0 = *(const ushort4*)ks;
      ushort4 a1 = *(const ushort4*)(ks + 4);
      ushort4 c0 = *(const ushort4*)vs;
      ushort4 c1 = *(const ushort4*)(vs + 4);
      float* kd = &Ks[r * 64 + lc];
      kd[0] = b2f(a0.x); kd[1] = b2f(a0.y); kd[2] = b2f(a0.z); kd[3] = b2f(a0.w);
      kd[4] = b2f(a1.x); kd[5] = b2f(a1.y); kd[6] = b2f(a1.z); kd[7] = b2f(a1.w);
      float* vd = &Vs[r * 64 + lc];
      vd[0] = b2f(c0.x); vd[1] = b2f(c0.y); vd[2] = b2f(c0.z); vd[3] = b2f(c0.w);
      vd[4] = b2f(c1.x); vd[5] = b2f(c1.y); vd[6] = b2f(c1.z); vd[7] = b2f(c1.w);
    }
    __syncthreads();
    #pragma unroll 8
    for (int tt = 0; tt < 64; ++tt) {
      float kv = Ks[tt * 64 + d1];
      #pragma unroll
      for (int j = 0; j < 16; ++j) acc[j] += kv * Vs[tt * 64 + d2b + j];
    }
  }
  float* Mo = Mbuf + (size_t)bh * 4096 + d1 * 64 + d2b;
  #pragma unroll
  for (int j = 0; j < 16; ++j) Mo[j] = acc[j] * 0.03125f;   // C^-0.5 = 1/32
}

// heads = Q @ M, written directly in concat layout cat[b,t, h*64+d]
__global__ __launch_bounds__(256)
void attn_h_kernel(const u16* __restrict__ qkv, const float* __restrict__ Mbuf,
                   u16* __restrict__ cat) {
  const int bh = blockIdx.x;
  const int tch = blockIdx.y;
  const int b = bh >> 4, h = bh & 15;
  __shared__ __align__(16) float Ms[64 * 64];
  __shared__ __align__(16) float Qs[64 * 65];
  const int tid = threadIdx.x;
  const float* Msrc = Mbuf + (size_t)bh * 4096;
  #pragma unroll
  for (int i = 0; i < 16; ++i) Ms[i * 256 + tid] = Msrc[i * 256 + tid];
  const u16* Qp = qkv + (size_t)(b * 1024 + tch * 64) * 3072 + h * 64;
  {
    const int lr = tid >> 3, lc = (tid & 7) * 8;
    #pragma unroll
    for (int it = 0; it < 2; ++it) {
      int r = it * 32 + lr;
      const u16* qs = Qp + (size_t)r * 3072 + lc;
      ushort4 a0 = *(const ushort4*)qs;
      ushort4 a1 = *(const ushort4*)(qs + 4);
      float* qd = &Qs[r * 65 + lc];
      qd[0] = b2f(a0.x); qd[1] = b2f(a0.y); qd[2] = b2f(a0.z); qd[3] = b2f(a0.w);
      qd[4] = b2f(a1.x); qd[5] = b2f(a1.y); qd[6] = b2f(a1.z); qd[7] = b2f(a1.w);
    }
  }
  __syncthreads();
  const int tl = tid >> 2, db = (tid & 3) * 16;
  float acc[16];
  #pragma unroll
  for (int j = 0; j < 16; ++j) acc[j] = 0.f;
  #pragma unroll 4
  for (int k = 0; k < 64; ++k) {
    float qv = Qs[tl * 65 + k];
    #pragma unroll
    for (int j = 0; j < 16; ++j) acc[j] += qv * Ms[k * 64 + db + j];
  }
  u16* Cp = cat + (size_t)(b * 1024 + tch * 64 + tl) * 1024 + h * 64 + db;
  ushort4 o0 = {f2b(acc[0]), f2b(acc[1]), f2b(acc[2]), f2b(acc[3])};
  ushort4 o1 = {f2b(acc[4]), f2b(acc[5]), f2b(acc[6]), f2b(acc[7])};
  ushort4 o2 = {f2b(acc[8]), f2b(acc[9]), f2b(acc[10]), f2b(acc[11])};
  ushort4 o3 = {f2b(acc[12]), f2b(acc[13]), f2b(acc[14]), f2b(acc[15])};
  *(ushort4*)(Cp + 0) = o0;
  *(ushort4*)(Cp + 4) = o1;
  *(ushort4*)(Cp + 8) = o2;
  *(ushort4*)(Cp + 12) = o3;
}

extern "C" void kernel_launch(void* const* d_in, const int* in_sizes, int n_in,
                              void* d_out, int out_size, void* d_ws, size_t ws_size,
                              hipStream_t stream) {
  (void)in_sizes; (void)n_in; (void)out_size; (void)ws_size;
  const float* x     = (const float*)d_in[0];
  const float* Wq    = (const float*)d_in[1];
  const float* bq    = (const float*)d_in[2];
  const float* Wk    = (const float*)d_in[3];
  const float* bk    = (const float*)d_in[4];
  const float* Wv    = (const float*)d_in[5];
  const float* bv    = (const float*)d_in[6];
  const float* Wp    = (const float*)d_in[7];
  const float* bp    = (const float*)d_in[8];
  const float* W1    = (const float*)d_in[9];
  const float* b1    = (const float*)d_in[10];
  const float* W2    = (const float*)d_in[11];
  const float* b2    = (const float*)d_in[12];
  const float* ln1w  = (const float*)d_in[13];
  const float* ln1b  = (const float*)d_in[14];
  const float* ln2w  = (const float*)d_in[15];
  const float* ln2b  = (const float*)d_in[16];

  char* ws = (char*)d_ws;
  u16* x1    = (u16*)(ws);                        // 16 MiB  [8192,1024] bf16
  u16* qkv   = (u16*)(ws + 16777216);             // 48 MiB  [8192,3072] bf16
  u16* cat   = (u16*)(ws + 67108864);             // 16 MiB  [8192,1024] bf16
  u16* yb    = (u16*)(ws + 83886080);             // 16 MiB  [8192,1024] bf16
  u16* x2    = (u16*)(ws + 100663296);            // 16 MiB  [8192,1024] bf16
  u16* WqkvT = (u16*)(ws + 117440512);            // 6 MiB   [3072,1024] bf16
  u16* WpT   = (u16*)(ws + 123731968);            // 2 MiB   [1024,1024] bf16
  u16* W1T   = (u16*)(ws + 125829120);            // 8 MiB   [4096,1024] bf16
  u16* W2T   = (u16*)(ws + 134217728);            // 8 MiB   [1024,4096] bf16
  float* Mb  = (float*)(ws + 142606336);          // 2 MiB   [128,64,64] fp32
  u16* hb    = (u16*)(ws + 16777216);             // 64 MiB, reuses dead qkv+cat

  static bool s_attr_done = false;
  if (!s_attr_done) {
    hipFuncSetAttribute((const void*)(&gemm_nt8<0>),
                        hipFuncAttributeMaxDynamicSharedMemorySize, 131072);
    hipFuncSetAttribute((const void*)(&gemm_nt8<1>),
                        hipFuncAttributeMaxDynamicSharedMemorySize, 131072);
    hipFuncSetAttribute((const void*)(&gemm_nt8<2>),
                        hipFuncAttributeMaxDynamicSharedMemorySize, 131072);
    hipFuncSetAttribute((const void*)(&gemm_nt8<3>),
                        hipFuncAttributeMaxDynamicSharedMemorySize, 131072);
    s_attr_done = true;
  }

  repack_qkv_tiled<<<dim3(16, 48), 256, 0, stream>>>(Wq, Wk, Wv, WqkvT);
  transpose_tiled<<<dim3(32, 32), 256, 0, stream>>>(Wp, WpT, 1024, 1024);
  transpose_tiled<<<dim3(128, 32), 256, 0, stream>>>(W1, W1T, 4096, 1024);
  transpose_tiled<<<dim3(32, 128), 256, 0, stream>>>(W2, W2T, 1024, 4096);

  ln_f32_kernel<<<8192, 256, 0, stream>>>(x, ln1w, ln1b, x1);

  gemm_nt8<0><<<dim3(12, 32), 512, 131072, stream>>>(x1, WqkvT, qkv, bq, bk, bv,
                                                     nullptr, 8192, 3072, 1024);
  attn_m_kernel<<<128, 256, 0, stream>>>(qkv, Mb);
  attn_h_kernel<<<dim3(128, 16), 256, 0, stream>>>(qkv, Mb, cat);

  gemm_nt8<1><<<dim3(4, 32), 512, 131072, stream>>>(cat, WpT, yb, bp, nullptr,
                                                    nullptr, x1, 8192, 1024, 1024);
  ln_bf16_kernel<<<8192, 256, 0, stream>>>(yb, ln2w, ln2b, x2);

  gemm_nt8<2><<<dim3(16, 32), 512, 131072, stream>>>(x2, W1T, hb, b1, nullptr,
                                                     nullptr, nullptr, 8192, 4096, 1024);
  gemm_nt8<3><<<dim3(4, 32), 512, 131072, stream>>>(hb, W2T, d_out, b2, nullptr,
                                                    nullptr, x2, 8192, 1024, 4096);
}

// Round 2
// 537.116 us; speedup vs baseline: 1.4481x; 1.4481x over previous
//
#include <hip/hip_runtime.h>

typedef unsigned short u16;
typedef unsigned int u32;
typedef unsigned long long u64;
typedef __attribute__((ext_vector_type(8))) short bf16x8;
typedef __attribute__((ext_vector_type(4))) float f32x4;

__device__ __forceinline__ float b2f(u16 v) {
  union { u32 u; float f; } c; c.u = ((u32)v) << 16; return c.f;
}
__device__ __forceinline__ u16 f2b(float f) {
  union { float f; u32 u; } c; c.f = f;
  return (u16)((c.u + 0x7fffu + ((c.u >> 16) & 1u)) >> 16);
}

// async global->LDS, 16B per lane (global_load_lds_dwordx4).
__device__ __forceinline__ void g2l16(const u16* g, u16* l) {
  __builtin_amdgcn_global_load_lds(
      (const __attribute__((address_space(1))) u32*)g,
      (__attribute__((address_space(3))) u32*)l,
      16, 0, 0);
}

// tanh-form GELU: verified round 1 (absmax unchanged at 0.0625).
// hw v_exp_f32 + v_rcp_f32, ~9 VALU ops vs ~60+ for erff.
__device__ __forceinline__ float gelu_fast(float x) {
  float z2 = -1.5957691216057308f * x * (1.0f + 0.044715f * x * x);  // -2z
  z2 = fminf(fmaxf(z2, -30.f), 30.f);
  float t = __expf(z2);
  return x * __builtin_amdgcn_rcpf(1.0f + t);
}

// ---------------- LDS-tiled weight repacks (fp32 in -> bf16 out) -------------
__global__ __launch_bounds__(256)
void repack_qkv_tiled(const float* __restrict__ Wq, const float* __restrict__ Wk,
                      const float* __restrict__ Wv, u16* __restrict__ WT) {
  __shared__ u16 tile[64][65];
  const int sh = blockIdx.y, sel = sh >> 4, h = sh & 15;
  const float* W = (sel == 0) ? Wq : ((sel == 1) ? Wk : Wv);
  const int k0 = blockIdx.x * 64;
  {
    const int d = threadIdx.x & 63, r = threadIdx.x >> 6;
    #pragma unroll
    for (int i = 0; i < 16; ++i) {
      int k = r * 16 + i;
      tile[k][d] = f2b(W[(size_t)h * 65536 + (size_t)(k0 + k) * 64 + d]);
    }
  }
  __syncthreads();
  {
    const int k = threadIdx.x & 63, dd = threadIdx.x >> 6;
    #pragma unroll
    for (int i = 0; i < 16; ++i) {
      int d2 = dd * 16 + i;
      WT[((size_t)sel * 1024 + h * 64 + d2) * 1024 + k0 + k] = tile[k][d2];
    }
  }
}

__global__ __launch_bounds__(256)
void transpose_tiled(const float* __restrict__ W, u16* __restrict__ WT,
                     int N, int K) {
  __shared__ u16 tile[32][33];
  const int bx = blockIdx.x * 32;   // n
  const int by = blockIdx.y * 32;   // k
  const int tx = threadIdx.x & 31, ty = threadIdx.x >> 5;
  #pragma unroll
  for (int i = 0; i < 4; ++i) {
    int k = ty + i * 8;
    tile[k][tx] = f2b(W[(size_t)(by + k) * N + bx + tx]);
  }
  __syncthreads();
  #pragma unroll
  for (int i = 0; i < 4; ++i) {
    int n = ty + i * 8;
    WT[(size_t)(bx + n) * K + by + tx] = tile[tx][n];
  }
}

// ---------------- LayerNorm (C=1024, EPS=1e-3), bf16 out ----------------
__global__ __launch_bounds__(256)
void ln_f32_kernel(const float* __restrict__ X, const float* __restrict__ G,
                   const float* __restrict__ Bt, u16* __restrict__ O) {
  const int row = blockIdx.x;
  const int tid = threadIdx.x;
  const float* xr = X + (size_t)row * 1024;
  float4 xv = *(const float4*)(xr + tid * 4);
  float v0 = xv.x, v1 = xv.y, v2 = xv.z, v3 = xv.w;
  float s = v0 + v1 + v2 + v3;
  float q = v0 * v0 + v1 * v1 + v2 * v2 + v3 * v3;
  #pragma unroll
  for (int off = 32; off > 0; off >>= 1) {
    s += __shfl_down(s, off);
    q += __shfl_down(q, off);
  }
  __shared__ float red[8];
  int wave = tid >> 6, lane = tid & 63;
  if (lane == 0) { red[wave] = s; red[4 + wave] = q; }
  __syncthreads();
  s = red[0] + red[1] + red[2] + red[3];
  q = red[4] + red[5] + red[6] + red[7];
  float mean = s * (1.f / 1024.f);
  float var = q * (1.f / 1024.f) - mean * mean;
  float rstd = rsqrtf(var + 1e-3f);
  float4 gv = *(const float4*)(G + tid * 4);
  float4 bv = *(const float4*)(Bt + tid * 4);
  ushort4 ov;
  ov.x = f2b((v0 - mean) * rstd * gv.x + bv.x);
  ov.y = f2b((v1 - mean) * rstd * gv.y + bv.y);
  ov.z = f2b((v2 - mean) * rstd * gv.z + bv.z);
  ov.w = f2b((v3 - mean) * rstd * gv.w + bv.w);
  *(ushort4*)(O + (size_t)row * 1024 + tid * 4) = ov;
}

__global__ __launch_bounds__(256)
void ln_bf16_kernel(const u16* __restrict__ X, const float* __restrict__ G,
                    const float* __restrict__ Bt, u16* __restrict__ O) {
  const int row = blockIdx.x;
  const int tid = threadIdx.x;
  const u16* xr = X + (size_t)row * 1024;
  ushort4 xv = *(const ushort4*)(xr + tid * 4);
  float v0 = b2f(xv.x), v1 = b2f(xv.y), v2 = b2f(xv.z), v3 = b2f(xv.w);
  float s = v0 + v1 + v2 + v3;
  float q = v0 * v0 + v1 * v1 + v2 * v2 + v3 * v3;
  #pragma unroll
  for (int off = 32; off > 0; off >>= 1) {
    s += __shfl_down(s, off);
    q += __shfl_down(q, off);
  }
  __shared__ float red[8];
  int wave = tid >> 6, lane = tid & 63;
  if (lane == 0) { red[wave] = s; red[4 + wave] = q; }
  __syncthreads();
  s = red[0] + red[1] + red[2] + red[3];
  q = red[4] + red[5] + red[6] + red[7];
  float mean = s * (1.f / 1024.f);
  float var = q * (1.f / 1024.f) - mean * mean;
  float rstd = rsqrtf(var + 1e-3f);
  float4 gv = *(const float4*)(G + tid * 4);
  float4 bv = *(const float4*)(Bt + tid * 4);
  ushort4 ov;
  ov.x = f2b((v0 - mean) * rstd * gv.x + bv.x);
  ov.y = f2b((v1 - mean) * rstd * gv.y + bv.y);
  ov.z = f2b((v2 - mean) * rstd * gv.z + bv.z);
  ov.w = f2b((v3 - mean) * rstd * gv.w + bv.w);
  *(ushort4*)(O + (size_t)row * 1024 + tid * 4) = ov;
}

// ---------------- NT GEMM: A[M,K] * BT[N,K]^T, bf16 in, fp32 acc -------------
// Proven 128x128-tile structure (628 us session best). BK=64 K-loop: 8x
// width-16 global_load_lds per iter, 32 MFMA per barrier pair. Row = 128B in
// LDS, so k-chunk slot is XOR-swizzled with (row&7) to spread fragment
// ds_read_b128 across all banks. Epilogue: swizzled LDS transpose ->
// coalesced 16B stores.
// NEW: 1-D grid + bijective XCD swizzle (T1, m204): consecutive swizzled ids
// stay on one XCD and share A-panels -> A fetched ~once per XCD instead of 8x.
// Requires gridDim.x % 8 == 0 (all our launches: 1536/512/2048/512).
// EPI 0: qkv 3-part bias; 1: bias+residual (bf16 out); 2: bias+GELU(fast);
// 3: bias+residual (fp32 out).
template <int EPI>
__global__ __launch_bounds__(256)
void gemm_nt(const u16* __restrict__ A, const u16* __restrict__ BT,
             void* __restrict__ Cout,
             const float* __restrict__ bias0, const float* __restrict__ bias1,
             const float* __restrict__ bias2, const u16* __restrict__ resid,
             int M, int N, int K) {
  __shared__ __align__(16) u16 smem[16384];     // As=[0:8192), Bs=[8192:16384)
  u16* As = smem;
  u16* Bs = smem + 8192;
  const int tid = threadIdx.x;

  // XCD-aware bijective block swizzle: xcd = bid&7 gets contiguous chunk.
  const u32 nb = gridDim.x;
  u32 bid = blockIdx.x;
  bid = (bid & 7) * (nb >> 3) + (bid >> 3);
  const u32 gx = (u32)N >> 7;                   // tiles along N
  const int m0 = (int)(bid / gx) * 128;
  const int n0 = (int)(bid % gx) * 128;

  const int wave = tid >> 6, lane = tid & 63;
  const int wm = wave & 1, wn = wave >> 1;
  const int quad = lane >> 4, l16 = lane & 15;

  f32x4 acc[4][4];
  #pragma unroll
  for (int i = 0; i < 4; ++i)
    #pragma unroll
    for (int j = 0; j < 4; ++j) acc[i][j] = (f32x4){0.f, 0.f, 0.f, 0.f};

  // staging: thread tid covers row rowS (+32,+64,+96), stored slot = tid&7.
  // Stored slot s of row r holds logical k-chunk s ^ (r&7).
  const int rowS = tid >> 3;                    // 0..31
  const int swz = ((tid & 7) ^ ((tid >> 3) & 7)) * 8;   // source k-offset
  const u16* aB = A + (size_t)(m0 + rowS) * K + swz;
  const u16* bB = BT + (size_t)(n0 + rowS) * K + swz;
  u16* aD = &As[(u32)tid * 8];
  u16* bD = &Bs[(u32)tid * 8];
  const size_t rstep = (size_t)32 * K;          // 32 rows down

  for (int k0 = 0; k0 < K; k0 += 64) {
    #pragma unroll
    for (int cc = 0; cc < 4; ++cc) {
      g2l16(aB + k0 + cc * rstep, aD + cc * 2048);
      g2l16(bB + k0 + cc * rstep, bD + cc * 2048);
    }
    __syncthreads();   // vmcnt drain -> 128x64 tiles staged
    #pragma unroll
    for (int ks = 0; ks < 2; ++ks) {
      // fragment row = wm*64+i*16+l16 -> row&7 = l16&7; logical chunk ks*4+quad
      const int sOff = (((ks * 4 + quad) ^ (l16 & 7)) * 8);
      bf16x8 aF[4], bF[4];
      #pragma unroll
      for (int i = 0; i < 4; ++i)
        aF[i] = *(const bf16x8*)&As[(wm * 64 + i * 16 + l16) * 64 + sOff];
      #pragma unroll
      for (int j = 0; j < 4; ++j)
        bF[j] = *(const bf16x8*)&Bs[(wn * 64 + j * 16 + l16) * 64 + sOff];
      #pragma unroll
      for (int i = 0; i < 4; ++i)
        #pragma unroll
        for (int j = 0; j < 4; ++j)
          acc[i][j] = __builtin_amdgcn_mfma_f32_16x16x32_bf16(aF[i], bF[j], acc[i][j], 0, 0, 0);
    }
    __syncthreads();   // frag reads done before next iter's staging overwrites
  }

  // ---- epilogue: stage 64x128 halves through LDS (16B-chunk XOR swizzle),
  // then coalesced stores. C/D layout: col=lane&15, row=quad*4+reg (m89).
  #pragma unroll
  for (int half = 0; half < 2; ++half) {
    if (wm == half) {
      #pragma unroll
      for (int i = 0; i < 4; ++i) {
        const int fsw = (i * 4 + quad) & 7;     // (lrow>>2)&7
        #pragma unroll
        for (int j = 0; j < 4; ++j) {
          const int chunk = (wn * 8 + j * 2 + (l16 >> 3)) ^ fsw;
          const int base = chunk * 8 + (l16 & 7);
          #pragma unroll
          for (int rr = 0; rr < 4; ++rr) {
            const int lrow = i * 16 + quad * 4 + rr;
            smem[lrow * 128 + base] = f2b(acc[i][j][rr]);
          }
        }
      }
    }
    __syncthreads();
    #pragma unroll
    for (int s = 0; s < 4; ++s) {
      const int lrow = s * 16 + (tid >> 4);
      const int chunk = tid & 15;
      const int fsw = (lrow >> 2) & 7;
      bf16x8 cv = *(const bf16x8*)&smem[lrow * 128 + ((chunk ^ fsw) * 8)];
      const int gr = m0 + half * 64 + lrow;
      const int gc = n0 + chunk * 8;
      const float* bp_ = bias0;
      int cb = gc;
      if (EPI == 0) {
        const int selb = gc >> 10;
        bp_ = (selb == 0) ? bias0 : ((selb == 1) ? bias1 : bias2);
        cb = gc & 1023;
      }
      float4 bv0 = *(const float4*)(bp_ + cb);
      float4 bv1 = *(const float4*)(bp_ + cb + 4);
      float vv[8];
      #pragma unroll
      for (int e = 0; e < 8; ++e) {
        float be = (e < 4) ? ((const float*)&bv0)[e] : ((const float*)&bv1)[e - 4];
        vv[e] = b2f(((const u16*)&cv)[e]) + be;
      }
      if (EPI == 2) {
        #pragma unroll
        for (int e = 0; e < 8; ++e) vv[e] = gelu_fast(vv[e]);
      }
      if (EPI == 1 || EPI == 3) {
        bf16x8 rv = *(const bf16x8*)(resid + (size_t)gr * N + gc);
        #pragma unroll
        for (int e = 0; e < 8; ++e) vv[e] += b2f(((const u16*)&rv)[e]);
      }
      if (EPI == 3) {
        float4 o0 = {vv[0], vv[1], vv[2], vv[3]};
        float4 o1 = {vv[4], vv[5], vv[6], vv[7]};
        float* op = (float*)Cout + (size_t)gr * N + gc;
        *(float4*)op = o0;
        *(float4*)(op + 4) = o1;
      } else {
        bf16x8 ov;
        #pragma unroll
        for (int e = 0; e < 8; ++e) ((u16*)&ov)[e] = f2b(vv[e]);
        *(bf16x8*)((u16*)Cout + (size_t)gr * N + gc) = ov;
      }
    }
    __syncthreads();   // half-0 reads done before half-1 overwrites
  }
}

// ---------------- attention (no softmax!): M = scale * K^T V per (b,h) -------
// Split over d2 halves (grid.y = 2) so 256 blocks cover the GPU (was 128 =
// half idle). Vs stride padded to 36 floats to spread store banks.
__global__ __launch_bounds__(256)
void attn_m_kernel(const u16* __restrict__ qkv, float* __restrict__ Mbuf) {
  const int bh = blockIdx.x;
  const int half = blockIdx.y;                  // d2 cols [half*32, half*32+32)
  const int b = bh >> 4, h = bh & 15;
  const u16* Kp = qkv + (size_t)b * 1024 * 3072 + 1024 + h * 64;
  const u16* Vp = Kp + 1024 + half * 32;
  __shared__ __align__(16) float Ks[64 * 64];
  __shared__ __align__(16) float Vs[64 * 36];
  const int tid = threadIdx.x;
  const int d1 = tid & 63, d2b = (tid >> 6) * 8;
  const int lr = tid >> 3, lc = (tid & 7) * 8;  // K staging: 32 rows x 8 cols
  const int vr = tid >> 2, vc = (tid & 3) * 8;  // V staging: 64 rows x 8 cols
  float acc[8];
  #pragma unroll
  for (int j = 0; j < 8; ++j) acc[j] = 0.f;
  for (int t0 = 0; t0 < 1024; t0 += 64) {
    __syncthreads();
    #pragma unroll
    for (int it = 0; it < 2; ++it) {
      int r = it * 32 + lr;
      const u16* ks = Kp + (size_t)(t0 + r) * 3072 + lc;
      ushort4 a0 = *(const ushort4*)ks;
      ushort4 a1 = *(const ushort4*)(ks + 4);
      float* kd = &Ks[r * 64 + lc];
      kd[0] = b2f(a0.x); kd[1] = b2f(a0.y); kd[2] = b2f(a0.z); kd[3] = b2f(a0.w);
      kd[4] = b2f(a1.x); kd[5] = b2f(a1.y); kd[6] = b2f(a1.z); kd[7] = b2f(a1.w);
    }
    {
      const u16* vs = Vp + (size_t)(t0 + vr) * 3072 + vc;
      ushort4 c0 = *(const ushort4*)vs;
      ushort4 c1 = *(const ushort4*)(vs + 4);
      float* vd = &Vs[vr * 36 + vc];
      vd[0] = b2f(c0.x); vd[1] = b2f(c0.y); vd[2] = b2f(c0.z); vd[3] = b2f(c0.w);
      vd[4] = b2f(c1.x); vd[5] = b2f(c1.y); vd[6] = b2f(c1.z); vd[7] = b2f(c1.w);
    }
    __syncthreads();
    #pragma unroll 8
    for (int tt = 0; tt < 64; ++tt) {
      float kv = Ks[tt * 64 + d1];
      #pragma unroll
      for (int j = 0; j < 8; ++j) acc[j] += kv * Vs[tt * 36 + d2b + j];
    }
  }
  float* Mo = Mbuf + (size_t)bh * 4096 + d1 * 64 + half * 32 + d2b;
  #pragma unroll
  for (int j = 0; j < 8; ++j) Mo[j] = acc[j] * 0.03125f;   // C^-0.5 = 1/32
}

// heads = Q @ M, written directly in concat layout cat[b,t, h*64+d]
__global__ __launch_bounds__(256)
void attn_h_kernel(const u16* __restrict__ qkv, const float* __restrict__ Mbuf,
                   u16* __restrict__ cat) {
  const int bh = blockIdx.x;
  const int tch = blockIdx.y;
  const int b = bh >> 4, h = bh & 15;
  __shared__ __align__(16) float Ms[64 * 64];
  __shared__ __align__(16) float Qs[64 * 65];
  const int tid = threadIdx.x;
  const float* Msrc = Mbuf + (size_t)bh * 4096;
  #pragma unroll
  for (int i = 0; i < 16; ++i) Ms[i * 256 + tid] = Msrc[i * 256 + tid];
  const u16* Qp = qkv + (size_t)(b * 1024 + tch * 64) * 3072 + h * 64;
  {
    const int lr = tid >> 3, lc = (tid & 7) * 8;
    #pragma unroll
    for (int it = 0; it < 2; ++it) {
      int r = it * 32 + lr;
      const u16* qs = Qp + (size_t)r * 3072 + lc;
      ushort4 a0 = *(const ushort4*)qs;
      ushort4 a1 = *(const ushort4*)(qs + 4);
      float* qd = &Qs[r * 65 + lc];
      qd[0] = b2f(a0.x); qd[1] = b2f(a0.y); qd[2] = b2f(a0.z); qd[3] = b2f(a0.w);
      qd[4] = b2f(a1.x); qd[5] = b2f(a1.y); qd[6] = b2f(a1.z); qd[7] = b2f(a1.w);
    }
  }
  __syncthreads();
  const int tl = tid >> 2, db = (tid & 3) * 16;
  float acc[16];
  #pragma unroll
  for (int j = 0; j < 16; ++j) acc[j] = 0.f;
  #pragma unroll 4
  for (int k = 0; k < 64; ++k) {
    float qv = Qs[tl * 65 + k];
    #pragma unroll
    for (int j = 0; j < 16; ++j) acc[j] += qv * Ms[k * 64 + db + j];
  }
  u16* Cp = cat + (size_t)(b * 1024 + tch * 64 + tl) * 1024 + h * 64 + db;
  ushort4 o0 = {f2b(acc[0]), f2b(acc[1]), f2b(acc[2]), f2b(acc[3])};
  ushort4 o1 = {f2b(acc[4]), f2b(acc[5]), f2b(acc[6]), f2b(acc[7])};
  ushort4 o2 = {f2b(acc[8]), f2b(acc[9]), f2b(acc[10]), f2b(acc[11])};
  ushort4 o3 = {f2b(acc[12]), f2b(acc[13]), f2b(acc[14]), f2b(acc[15])};
  *(ushort4*)(Cp + 0) = o0;
  *(ushort4*)(Cp + 4) = o1;
  *(ushort4*)(Cp + 8) = o2;
  *(ushort4*)(Cp + 12) = o3;
}

extern "C" void kernel_launch(void* const* d_in, const int* in_sizes, int n_in,
                              void* d_out, int out_size, void* d_ws, size_t ws_size,
                              hipStream_t stream) {
  (void)in_sizes; (void)n_in; (void)out_size; (void)ws_size;
  const float* x     = (const float*)d_in[0];
  const float* Wq    = (const float*)d_in[1];
  const float* bq    = (const float*)d_in[2];
  const float* Wk    = (const float*)d_in[3];
  const float* bk    = (const float*)d_in[4];
  const float* Wv    = (const float*)d_in[5];
  const float* bv    = (const float*)d_in[6];
  const float* Wp    = (const float*)d_in[7];
  const float* bp    = (const float*)d_in[8];
  const float* W1    = (const float*)d_in[9];
  const float* b1    = (const float*)d_in[10];
  const float* W2    = (const float*)d_in[11];
  const float* b2    = (const float*)d_in[12];
  const float* ln1w  = (const float*)d_in[13];
  const float* ln1b  = (const float*)d_in[14];
  const float* ln2w  = (const float*)d_in[15];
  const float* ln2b  = (const float*)d_in[16];

  char* ws = (char*)d_ws;
  u16* x1    = (u16*)(ws);                        // 16 MiB  [8192,1024] bf16
  u16* qkv   = (u16*)(ws + 16777216);             // 48 MiB  [8192,3072] bf16
  u16* cat   = (u16*)(ws + 67108864);             // 16 MiB  [8192,1024] bf16
  u16* yb    = (u16*)(ws + 83886080);             // 16 MiB  [8192,1024] bf16
  u16* x2    = (u16*)(ws + 100663296);            // 16 MiB  [8192,1024] bf16
  u16* WqkvT = (u16*)(ws + 117440512);            // 6 MiB   [3072,1024] bf16
  u16* WpT   = (u16*)(ws + 123731968);            // 2 MiB   [1024,1024] bf16
  u16* W1T   = (u16*)(ws + 125829120);            // 8 MiB   [4096,1024] bf16
  u16* W2T   = (u16*)(ws + 134217728);            // 8 MiB   [1024,4096] bf16
  float* Mb  = (float*)(ws + 142606336);          // 2 MiB   [128,64,64] fp32
  u16* hb    = (u16*)(ws + 16777216);             // 64 MiB, reuses dead qkv+cat

  repack_qkv_tiled<<<dim3(16, 48), 256, 0, stream>>>(Wq, Wk, Wv, WqkvT);
  transpose_tiled<<<dim3(32, 32), 256, 0, stream>>>(Wp, WpT, 1024, 1024);
  transpose_tiled<<<dim3(128, 32), 256, 0, stream>>>(W1, W1T, 4096, 1024);
  transpose_tiled<<<dim3(32, 128), 256, 0, stream>>>(W2, W2T, 1024, 4096);

  ln_f32_kernel<<<8192, 256, 0, stream>>>(x, ln1w, ln1b, x1);

  // 1-D grids (XCD swizzle inside the kernel; all counts % 8 == 0)
  gemm_nt<0><<<1536, 256, 0, stream>>>(x1, WqkvT, qkv, bq, bk, bv, nullptr,
                                       8192, 3072, 1024);
  attn_m_kernel<<<dim3(128, 2), 256, 0, stream>>>(qkv, Mb);
  attn_h_kernel<<<dim3(128, 16), 256, 0, stream>>>(qkv, Mb, cat);

  gemm_nt<1><<<512, 256, 0, stream>>>(cat, WpT, yb, bp, nullptr, nullptr, x1,
                                      8192, 1024, 1024);
  ln_bf16_kernel<<<8192, 256, 0, stream>>>(yb, ln2w, ln2b, x2);

  gemm_nt<2><<<2048, 256, 0, stream>>>(x2, W1T, hb, b1, nullptr, nullptr, nullptr,
                                       8192, 4096, 1024);
  gemm_nt<3><<<512, 256, 0, stream>>>(hb, W2T, d_out, b2, nullptr, nullptr, x2,
                                      8192, 1024, 4096);
}

// Round 3
// 523.400 us; speedup vs baseline: 1.4860x; 1.0262x over previous
//
#include <hip/hip_runtime.h>

typedef unsigned short u16;
typedef unsigned int u32;
typedef unsigned long long u64;
typedef __attribute__((ext_vector_type(8))) short bf16x8;
typedef __attribute__((ext_vector_type(4))) float f32x4;

__device__ __forceinline__ float b2f(u16 v) {
  union { u32 u; float f; } c; c.u = ((u32)v) << 16; return c.f;
}
__device__ __forceinline__ u16 f2b(float f) {
  union { float f; u32 u; } c; c.f = f;
  return (u16)((c.u + 0x7fffu + ((c.u >> 16) & 1u)) >> 16);
}

// async global->LDS, 16B per lane (global_load_lds_dwordx4).
__device__ __forceinline__ void g2l16(const u16* g, u16* l) {
  __builtin_amdgcn_global_load_lds(
      (const __attribute__((address_space(1))) u32*)g,
      (__attribute__((address_space(3))) u32*)l,
      16, 0, 0);
}

// tanh-form GELU: verified round 1/2 (absmax unchanged at 0.0625).
__device__ __forceinline__ float gelu_fast(float x) {
  float z2 = -1.5957691216057308f * x * (1.0f + 0.044715f * x * x);  // -2z
  z2 = fminf(fmaxf(z2, -30.f), 30.f);
  float t = __expf(z2);
  return x * __builtin_amdgcn_rcpf(1.0f + t);
}

// ---------------- LDS-tiled weight repacks (fp32 in -> bf16 out) -------------
__global__ __launch_bounds__(256)
void repack_qkv_tiled(const float* __restrict__ Wq, const float* __restrict__ Wk,
                      const float* __restrict__ Wv, u16* __restrict__ WT) {
  __shared__ u16 tile[64][65];
  const int sh = blockIdx.y, sel = sh >> 4, h = sh & 15;
  const float* W = (sel == 0) ? Wq : ((sel == 1) ? Wk : Wv);
  const int k0 = blockIdx.x * 64;
  {
    const int d = threadIdx.x & 63, r = threadIdx.x >> 6;
    #pragma unroll
    for (int i = 0; i < 16; ++i) {
      int k = r * 16 + i;
      tile[k][d] = f2b(W[(size_t)h * 65536 + (size_t)(k0 + k) * 64 + d]);
    }
  }
  __syncthreads();
  {
    const int k = threadIdx.x & 63, dd = threadIdx.x >> 6;
    #pragma unroll
    for (int i = 0; i < 16; ++i) {
      int d2 = dd * 16 + i;
      WT[((size_t)sel * 1024 + h * 64 + d2) * 1024 + k0 + k] = tile[k][d2];
    }
  }
}

__global__ __launch_bounds__(256)
void transpose_tiled(const float* __restrict__ W, u16* __restrict__ WT,
                     int N, int K) {
  __shared__ u16 tile[32][33];
  const int bx = blockIdx.x * 32;   // n
  const int by = blockIdx.y * 32;   // k
  const int tx = threadIdx.x & 31, ty = threadIdx.x >> 5;
  #pragma unroll
  for (int i = 0; i < 4; ++i) {
    int k = ty + i * 8;
    tile[k][tx] = f2b(W[(size_t)(by + k) * N + bx + tx]);
  }
  __syncthreads();
  #pragma unroll
  for (int i = 0; i < 4; ++i) {
    int n = ty + i * 8;
    WT[(size_t)(bx + n) * K + by + tx] = tile[tx][n];
  }
}

// ---------------- LayerNorm (C=1024, EPS=1e-3), bf16 out ----------------
__global__ __launch_bounds__(256)
void ln_f32_kernel(const float* __restrict__ X, const float* __restrict__ G,
                   const float* __restrict__ Bt, u16* __restrict__ O) {
  const int row = blockIdx.x;
  const int tid = threadIdx.x;
  const float* xr = X + (size_t)row * 1024;
  float4 xv = *(const float4*)(xr + tid * 4);
  float v0 = xv.x, v1 = xv.y, v2 = xv.z, v3 = xv.w;
  float s = v0 + v1 + v2 + v3;
  float q = v0 * v0 + v1 * v1 + v2 * v2 + v3 * v3;
  #pragma unroll
  for (int off = 32; off > 0; off >>= 1) {
    s += __shfl_down(s, off);
    q += __shfl_down(q, off);
  }
  __shared__ float red[8];
  int wave = tid >> 6, lane = tid & 63;
  if (lane == 0) { red[wave] = s; red[4 + wave] = q; }
  __syncthreads();
  s = red[0] + red[1] + red[2] + red[3];
  q = red[4] + red[5] + red[6] + red[7];
  float mean = s * (1.f / 1024.f);
  float var = q * (1.f / 1024.f) - mean * mean;
  float rstd = rsqrtf(var + 1e-3f);
  float4 gv = *(const float4*)(G + tid * 4);
  float4 bv = *(const float4*)(Bt + tid * 4);
  ushort4 ov;
  ov.x = f2b((v0 - mean) * rstd * gv.x + bv.x);
  ov.y = f2b((v1 - mean) * rstd * gv.y + bv.y);
  ov.z = f2b((v2 - mean) * rstd * gv.z + bv.z);
  ov.w = f2b((v3 - mean) * rstd * gv.w + bv.w);
  *(ushort4*)(O + (size_t)row * 1024 + tid * 4) = ov;
}

__global__ __launch_bounds__(256)
void ln_bf16_kernel(const u16* __restrict__ X, const float* __restrict__ G,
                    const float* __restrict__ Bt, u16* __restrict__ O) {
  const int row = blockIdx.x;
  const int tid = threadIdx.x;
  const u16* xr = X + (size_t)row * 1024;
  ushort4 xv = *(const ushort4*)(xr + tid * 4);
  float v0 = b2f(xv.x), v1 = b2f(xv.y), v2 = b2f(xv.z), v3 = b2f(xv.w);
  float s = v0 + v1 + v2 + v3;
  float q = v0 * v0 + v1 * v1 + v2 * v2 + v3 * v3;
  #pragma unroll
  for (int off = 32; off > 0; off >>= 1) {
    s += __shfl_down(s, off);
    q += __shfl_down(q, off);
  }
  __shared__ float red[8];
  int wave = tid >> 6, lane = tid & 63;
  if (lane == 0) { red[wave] = s; red[4 + wave] = q; }
  __syncthreads();
  s = red[0] + red[1] + red[2] + red[3];
  q = red[4] + red[5] + red[6] + red[7];
  float mean = s * (1.f / 1024.f);
  float var = q * (1.f / 1024.f) - mean * mean;
  float rstd = rsqrtf(var + 1e-3f);
  float4 gv = *(const float4*)(G + tid * 4);
  float4 bv = *(const float4*)(Bt + tid * 4);
  ushort4 ov;
  ov.x = f2b((v0 - mean) * rstd * gv.x + bv.x);
  ov.y = f2b((v1 - mean) * rstd * gv.y + bv.y);
  ov.z = f2b((v2 - mean) * rstd * gv.z + bv.z);
  ov.w = f2b((v3 - mean) * rstd * gv.w + bv.w);
  *(ushort4*)(O + (size_t)row * 1024 + tid * 4) = ov;
}

// ---------------- NT GEMM: A[M,K] * BT[N,K]^T, bf16 in, fp32 acc -------------
// 128x128 tile, BK=64, NOW ping-pong double-buffered LDS (64 KiB):
//   As(p) = smem[p*8192], Bs(p) = smem[16384 + p*8192].
// Per K-iter: counted wait (only tile t's 8 loads outstanding) + ONE raw
// s_barrier -> 16 ds_read_b128 frags -> issue tile t+1's 8 global_load_lds
// into buffer p^1 -> 32 MFMA. Loads for t+1 fly during t's MFMA region
// (issue-early/wait-late), and the barrier count is halved vs the old
// {drain, MFMA, barrier} x2 structure. Safety: the top-of-iter barrier
// orders all waves' iter t-1 fragment reads (complete, since MFMA consumed
// them) before buffer p^1 is overwritten.
// Row = 128B in LDS; 16B k-chunk slot XOR-swizzled with (row&7) (T2).
// Epilogue reuses smem[0:16384] for the swizzled C transpose.
// EPI 0: qkv 3-part bias; 1: bias+residual (bf16 out); 2: bias+GELU(fast);
// 3: bias+residual (fp32 out).
template <int EPI>
__global__ __launch_bounds__(256)
void gemm_nt(const u16* __restrict__ A, const u16* __restrict__ BT,
             void* __restrict__ Cout,
             const float* __restrict__ bias0, const float* __restrict__ bias1,
             const float* __restrict__ bias2, const u16* __restrict__ resid,
             int M, int N, int K) {
  __shared__ __align__(16) u16 smem[32768];     // 64 KiB: A0,A1,B0,B1
  const int tid = threadIdx.x;
  const int m0 = blockIdx.y * 128;
  const int n0 = blockIdx.x * 128;
  const int wave = tid >> 6, lane = tid & 63;
  const int wm = wave & 1, wn = wave >> 1;
  const int quad = lane >> 4, l16 = lane & 15;

  f32x4 acc[4][4];
  #pragma unroll
  for (int i = 0; i < 4; ++i)
    #pragma unroll
    for (int j = 0; j < 4; ++j) acc[i][j] = (f32x4){0.f, 0.f, 0.f, 0.f};

  // staging: thread tid covers row rowS (+32,+64,+96), stored slot = tid&7.
  // Stored slot s of row r holds logical k-chunk s ^ (r&7).
  const int rowS = tid >> 3;                    // 0..31
  const int swz = ((tid & 7) ^ ((tid >> 3) & 7)) * 8;   // source k-offset
  const u16* aB = A + (size_t)(m0 + rowS) * K + swz;
  const u16* bB = BT + (size_t)(n0 + rowS) * K + swz;
  const size_t rstep = (size_t)32 * K;          // 32 rows down

  const int nt = K >> 6;

  // issue the 8 global_load_lds for K-tile kt into buffer p
  auto stage = [&](int p, int kt) {
    u16* aD = &smem[(u32)p * 8192 + (u32)tid * 8];
    u16* bD = &smem[16384u + (u32)p * 8192 + (u32)tid * 8];
    const int k0 = kt * 64;
    #pragma unroll
    for (int cc = 0; cc < 4; ++cc) {
      g2l16(aB + k0 + cc * rstep, aD + cc * 2048);
      g2l16(bB + k0 + cc * rstep, bD + cc * 2048);
    }
  };

  stage(0, 0);   // prologue: tile 0 into buffer 0

  for (int t = 0; t < nt; ++t) {
    const int p = t & 1;
    // only tile t's 8 loads are outstanding here (t+1 not yet issued)
    asm volatile("s_waitcnt vmcnt(0)" ::: "memory");
    __builtin_amdgcn_s_barrier();
    const u16* As = &smem[(u32)p * 8192];
    const u16* Bs = &smem[16384u + (u32)p * 8192];

    bf16x8 aF[2][4], bF[2][4];
    #pragma unroll
    for (int ks = 0; ks < 2; ++ks) {
      // fragment row = wm*64+i*16+l16 -> row&7 = l16&7; logical chunk ks*4+quad
      const int sOff = (((ks * 4 + quad) ^ (l16 & 7)) * 8);
      #pragma unroll
      for (int i = 0; i < 4; ++i)
        aF[ks][i] = *(const bf16x8*)&As[(wm * 64 + i * 16 + l16) * 64 + sOff];
      #pragma unroll
      for (int j = 0; j < 4; ++j)
        bF[ks][j] = *(const bf16x8*)&Bs[(wn * 64 + j * 16 + l16) * 64 + sOff];
    }
    if (t + 1 < nt) stage(p ^ 1, t + 1);   // prefetch flies under the MFMAs
    #pragma unroll
    for (int ks = 0; ks < 2; ++ks)
      #pragma unroll
      for (int i = 0; i < 4; ++i)
        #pragma unroll
        for (int j = 0; j < 4; ++j)
          acc[i][j] = __builtin_amdgcn_mfma_f32_16x16x32_bf16(
              aF[ks][i], bF[ks][j], acc[i][j], 0, 0, 0);
  }
  __syncthreads();   // K-loop reads done before epilogue overwrites smem

  // ---- epilogue: stage 64x128 halves through LDS (16B-chunk XOR swizzle),
  // then coalesced stores. C/D layout: col=lane&15, row=quad*4+reg (m89).
  #pragma unroll
  for (int half = 0; half < 2; ++half) {
    if (wm == half) {
      #pragma unroll
      for (int i = 0; i < 4; ++i) {
        const int fsw = (i * 4 + quad) & 7;     // (lrow>>2)&7
        #pragma unroll
        for (int j = 0; j < 4; ++j) {
          const int chunk = (wn * 8 + j * 2 + (l16 >> 3)) ^ fsw;
          const int base = chunk * 8 + (l16 & 7);
          #pragma unroll
          for (int rr = 0; rr < 4; ++rr) {
            const int lrow = i * 16 + quad * 4 + rr;
            smem[lrow * 128 + base] = f2b(acc[i][j][rr]);
          }
        }
      }
    }
    __syncthreads();
    #pragma unroll
    for (int s = 0; s < 4; ++s) {
      const int lrow = s * 16 + (tid >> 4);
      const int chunk = tid & 15;
      const int fsw = (lrow >> 2) & 7;
      bf16x8 cv = *(const bf16x8*)&smem[lrow * 128 + ((chunk ^ fsw) * 8)];
      const int gr = m0 + half * 64 + lrow;
      const int gc = n0 + chunk * 8;
      const float* bp_ = bias0;
      int cb = gc;
      if (EPI == 0) {
        const int selb = gc >> 10;
        bp_ = (selb == 0) ? bias0 : ((selb == 1) ? bias1 : bias2);
        cb = gc & 1023;
      }
      float4 bv0 = *(const float4*)(bp_ + cb);
      float4 bv1 = *(const float4*)(bp_ + cb + 4);
      float vv[8];
      #pragma unroll
      for (int e = 0; e < 8; ++e) {
        float be = (e < 4) ? ((const float*)&bv0)[e] : ((const float*)&bv1)[e - 4];
        vv[e] = b2f(((const u16*)&cv)[e]) + be;
      }
      if (EPI == 2) {
        #pragma unroll
        for (int e = 0; e < 8; ++e) vv[e] = gelu_fast(vv[e]);
      }
      if (EPI == 1 || EPI == 3) {
        bf16x8 rv = *(const bf16x8*)(resid + (size_t)gr * N + gc);
        #pragma unroll
        for (int e = 0; e < 8; ++e) vv[e] += b2f(((const u16*)&rv)[e]);
      }
      if (EPI == 3) {
        float4 o0 = {vv[0], vv[1], vv[2], vv[3]};
        float4 o1 = {vv[4], vv[5], vv[6], vv[7]};
        float* op = (float*)Cout + (size_t)gr * N + gc;
        *(float4*)op = o0;
        *(float4*)(op + 4) = o1;
      } else {
        bf16x8 ov;
        #pragma unroll
        for (int e = 0; e < 8; ++e) ((u16*)&ov)[e] = f2b(vv[e]);
        *(bf16x8*)((u16*)Cout + (size_t)gr * N + gc) = ov;
      }
    }
    __syncthreads();   // half-0 reads done before half-1 overwrites
  }
}

// ---------------- attention (no softmax!): M = scale * K^T V per (b,h) -------
// Split over d2 halves (grid.y = 2) so 256 blocks cover the GPU.
__global__ __launch_bounds__(256)
void attn_m_kernel(const u16* __restrict__ qkv, float* __restrict__ Mbuf) {
  const int bh = blockIdx.x;
  const int half = blockIdx.y;                  // d2 cols [half*32, half*32+32)
  const int b = bh >> 4, h = bh & 15;
  const u16* Kp = qkv + (size_t)b * 1024 * 3072 + 1024 + h * 64;
  const u16* Vp = Kp + 1024 + half * 32;
  __shared__ __align__(16) float Ks[64 * 64];
  __shared__ __align__(16) float Vs[64 * 36];
  const int tid = threadIdx.x;
  const int d1 = tid & 63, d2b = (tid >> 6) * 8;
  const int lr = tid >> 3, lc = (tid & 7) * 8;  // K staging: 32 rows x 8 cols
  const int vr = tid >> 2, vc = (tid & 3) * 8;  // V staging: 64 rows x 8 cols
  float acc[8];
  #pragma unroll
  for (int j = 0; j < 8; ++j) acc[j] = 0.f;
  for (int t0 = 0; t0 < 1024; t0 += 64) {
    __syncthreads();
    #pragma unroll
    for (int it = 0; it < 2; ++it) {
      int r = it * 32 + lr;
      const u16* ks = Kp + (size_t)(t0 + r) * 3072 + lc;
      ushort4 a0 = *(const ushort4*)ks;
      ushort4 a1 = *(const ushort4*)(ks + 4);
      float* kd = &Ks[r * 64 + lc];
      kd[0] = b2f(a0.x); kd[1] = b2f(a0.y); kd[2] = b2f(a0.z); kd[3] = b2f(a0.w);
      kd[4] = b2f(a1.x); kd[5] = b2f(a1.y); kd[6] = b2f(a1.z); kd[7] = b2f(a1.w);
    }
    {
      const u16* vs = Vp + (size_t)(t0 + vr) * 3072 + vc;
      ushort4 c0 = *(const ushort4*)vs;
      ushort4 c1 = *(const ushort4*)(vs + 4);
      float* vd = &Vs[vr * 36 + vc];
      vd[0] = b2f(c0.x); vd[1] = b2f(c0.y); vd[2] = b2f(c0.z); vd[3] = b2f(c0.w);
      vd[4] = b2f(c1.x); vd[5] = b2f(c1.y); vd[6] = b2f(c1.z); vd[7] = b2f(c1.w);
    }
    __syncthreads();
    #pragma unroll 8
    for (int tt = 0; tt < 64; ++tt) {
      float kv = Ks[tt * 64 + d1];
      #pragma unroll
      for (int j = 0; j < 8; ++j) acc[j] += kv * Vs[tt * 36 + d2b + j];
    }
  }
  float* Mo = Mbuf + (size_t)bh * 4096 + d1 * 64 + half * 32 + d2b;
  #pragma unroll
  for (int j = 0; j < 8; ++j) Mo[j] = acc[j] * 0.03125f;   // C^-0.5 = 1/32
}

// heads = Q @ M, written directly in concat layout cat[b,t, h*64+d]
__global__ __launch_bounds__(256)
void attn_h_kernel(const u16* __restrict__ qkv, const float* __restrict__ Mbuf,
                   u16* __restrict__ cat) {
  const int bh = blockIdx.x;
  const int tch = blockIdx.y;
  const int b = bh >> 4, h = bh & 15;
  __shared__ __align__(16) float Ms[64 * 64];
  __shared__ __align__(16) float Qs[64 * 65];
  const int tid = threadIdx.x;
  const float* Msrc = Mbuf + (size_t)bh * 4096;
  #pragma unroll
  for (int i = 0; i < 16; ++i) Ms[i * 256 + tid] = Msrc[i * 256 + tid];
  const u16* Qp = qkv + (size_t)(b * 1024 + tch * 64) * 3072 + h * 64;
  {
    const int lr = tid >> 3, lc = (tid & 7) * 8;
    #pragma unroll
    for (int it = 0; it < 2; ++it) {
      int r = it * 32 + lr;
      const u16* qs = Qp + (size_t)r * 3072 + lc;
      ushort4 a0 = *(const ushort4*)qs;
      ushort4 a1 = *(const ushort4*)(qs + 4);
      float* qd = &Qs[r * 65 + lc];
      qd[0] = b2f(a0.x); qd[1] = b2f(a0.y); qd[2] = b2f(a0.z); qd[3] = b2f(a0.w);
      qd[4] = b2f(a1.x); qd[5] = b2f(a1.y); qd[6] = b2f(a1.z); qd[7] = b2f(a1.w);
    }
  }
  __syncthreads();
  const int tl = tid >> 2, db = (tid & 3) * 16;
  float acc[16];
  #pragma unroll
  for (int j = 0; j < 16; ++j) acc[j] = 0.f;
  #pragma unroll 4
  for (int k = 0; k < 64; ++k) {
    float qv = Qs[tl * 65 + k];
    #pragma unroll
    for (int j = 0; j < 16; ++j) acc[j] += qv * Ms[k * 64 + db + j];
  }
  u16* Cp = cat + (size_t)(b * 1024 + tch * 64 + tl) * 1024 + h * 64 + db;
  ushort4 o0 = {f2b(acc[0]), f2b(acc[1]), f2b(acc[2]), f2b(acc[3])};
  ushort4 o1 = {f2b(acc[4]), f2b(acc[5]), f2b(acc[6]), f2b(acc[7])};
  ushort4 o2 = {f2b(acc[8]), f2b(acc[9]), f2b(acc[10]), f2b(acc[11])};
  ushort4 o3 = {f2b(acc[12]), f2b(acc[13]), f2b(acc[14]), f2b(acc[15])};
  *(ushort4*)(Cp + 0) = o0;
  *(ushort4*)(Cp + 4) = o1;
  *(ushort4*)(Cp + 8) = o2;
  *(ushort4*)(Cp + 12) = o3;
}

extern "C" void kernel_launch(void* const* d_in, const int* in_sizes, int n_in,
                              void* d_out, int out_size, void* d_ws, size_t ws_size,
                              hipStream_t stream) {
  (void)in_sizes; (void)n_in; (void)out_size; (void)ws_size;
  const float* x     = (const float*)d_in[0];
  const float* Wq    = (const float*)d_in[1];
  const float* bq    = (const float*)d_in[2];
  const float* Wk    = (const float*)d_in[3];
  const float* bk    = (const float*)d_in[4];
  const float* Wv    = (const float*)d_in[5];
  const float* bv    = (const float*)d_in[6];
  const float* Wp    = (const float*)d_in[7];
  const float* bp    = (const float*)d_in[8];
  const float* W1    = (const float*)d_in[9];
  const float* b1    = (const float*)d_in[10];
  const float* W2    = (const float*)d_in[11];
  const float* b2    = (const float*)d_in[12];
  const float* ln1w  = (const float*)d_in[13];
  const float* ln1b  = (const float*)d_in[14];
  const float* ln2w  = (const float*)d_in[15];
  const float* ln2b  = (const float*)d_in[16];

  char* ws = (char*)d_ws;
  u16* x1    = (u16*)(ws);                        // 16 MiB  [8192,1024] bf16
  u16* qkv   = (u16*)(ws + 16777216);             // 48 MiB  [8192,3072] bf16
  u16* cat   = (u16*)(ws + 67108864);             // 16 MiB  [8192,1024] bf16
  u16* yb    = (u16*)(ws + 83886080);             // 16 MiB  [8192,1024] bf16
  u16* x2    = (u16*)(ws + 100663296);            // 16 MiB  [8192,1024] bf16
  u16* WqkvT = (u16*)(ws + 117440512);            // 6 MiB   [3072,1024] bf16
  u16* WpT   = (u16*)(ws + 123731968);            // 2 MiB   [1024,1024] bf16
  u16* W1T   = (u16*)(ws + 125829120);            // 8 MiB   [4096,1024] bf16
  u16* W2T   = (u16*)(ws + 134217728);            // 8 MiB   [1024,4096] bf16
  float* Mb  = (float*)(ws + 142606336);          // 2 MiB   [128,64,64] fp32
  u16* hb    = (u16*)(ws + 16777216);             // 64 MiB, reuses dead qkv+cat

  repack_qkv_tiled<<<dim3(16, 48), 256, 0, stream>>>(Wq, Wk, Wv, WqkvT);
  transpose_tiled<<<dim3(32, 32), 256, 0, stream>>>(Wp, WpT, 1024, 1024);
  transpose_tiled<<<dim3(128, 32), 256, 0, stream>>>(W1, W1T, 4096, 1024);
  transpose_tiled<<<dim3(32, 128), 256, 0, stream>>>(W2, W2T, 1024, 4096);

  ln_f32_kernel<<<8192, 256, 0, stream>>>(x, ln1w, ln1b, x1);

  gemm_nt<0><<<dim3(24, 64), 256, 0, stream>>>(x1, WqkvT, qkv, bq, bk, bv, nullptr,
                                               8192, 3072, 1024);
  attn_m_kernel<<<dim3(128, 2), 256, 0, stream>>>(qkv, Mb);
  attn_h_kernel<<<dim3(128, 16), 256, 0, stream>>>(qkv, Mb, cat);

  gemm_nt<1><<<dim3(8, 64), 256, 0, stream>>>(cat, WpT, yb, bp, nullptr, nullptr, x1,
                                              8192, 1024, 1024);
  ln_bf16_kernel<<<8192, 256, 0, stream>>>(yb, ln2w, ln2b, x2);

  gemm_nt<2><<<dim3(32, 64), 256, 0, stream>>>(x2, W1T, hb, b1, nullptr, nullptr, nullptr,
                                               8192, 4096, 1024);
  gemm_nt<3><<<dim3(8, 64), 256, 0, stream>>>(hb, W2T, d_out, b2, nullptr, nullptr, x2,
                                              8192, 1024, 4096);
}

// Round 4
// 510.503 us; speedup vs baseline: 1.5236x; 1.0253x over previous
//
#include <hip/hip_runtime.h>

typedef unsigned short u16;
typedef unsigned int u32;
typedef unsigned long long u64;
typedef __attribute__((ext_vector_type(8))) short bf16x8;
typedef __attribute__((ext_vector_type(4))) float f32x4;

__device__ __forceinline__ float b2f(u16 v) {
  union { u32 u; float f; } c; c.u = ((u32)v) << 16; return c.f;
}
__device__ __forceinline__ u16 f2b(float f) {
  union { float f; u32 u; } c; c.f = f;
  return (u16)((c.u + 0x7fffu + ((c.u >> 16) & 1u)) >> 16);
}

// async global->LDS, 16B per lane (global_load_lds_dwordx4).
__device__ __forceinline__ void g2l16(const u16* g, u16* l) {
  __builtin_amdgcn_global_load_lds(
      (const __attribute__((address_space(1))) u32*)g,
      (__attribute__((address_space(3))) u32*)l,
      16, 0, 0);
}

// tanh-form GELU: verified rounds 1-3 (absmax unchanged at 0.0625).
__device__ __forceinline__ float gelu_fast(float x) {
  float z2 = -1.5957691216057308f * x * (1.0f + 0.044715f * x * x);  // -2z
  z2 = fminf(fmaxf(z2, -30.f), 30.f);
  float t = __expf(z2);
  return x * __builtin_amdgcn_rcpf(1.0f + t);
}

// ---------------- LDS-tiled weight repacks (fp32 in -> bf16 out) -------------
__global__ __launch_bounds__(256)
void repack_qkv_tiled(const float* __restrict__ Wq, const float* __restrict__ Wk,
                      const float* __restrict__ Wv, u16* __restrict__ WT) {
  __shared__ u16 tile[64][65];
  const int sh = blockIdx.y, sel = sh >> 4, h = sh & 15;
  const float* W = (sel == 0) ? Wq : ((sel == 1) ? Wk : Wv);
  const int k0 = blockIdx.x * 64;
  {
    const int d = threadIdx.x & 63, r = threadIdx.x >> 6;
    #pragma unroll
    for (int i = 0; i < 16; ++i) {
      int k = r * 16 + i;
      tile[k][d] = f2b(W[(size_t)h * 65536 + (size_t)(k0 + k) * 64 + d]);
    }
  }
  __syncthreads();
  {
    const int k = threadIdx.x & 63, dd = threadIdx.x >> 6;
    #pragma unroll
    for (int i = 0; i < 16; ++i) {
      int d2 = dd * 16 + i;
      WT[((size_t)sel * 1024 + h * 64 + d2) * 1024 + k0 + k] = tile[k][d2];
    }
  }
}

__global__ __launch_bounds__(256)
void transpose_tiled(const float* __restrict__ W, u16* __restrict__ WT,
                     int N, int K) {
  __shared__ u16 tile[32][33];
  const int bx = blockIdx.x * 32;   // n
  const int by = blockIdx.y * 32;   // k
  const int tx = threadIdx.x & 31, ty = threadIdx.x >> 5;
  #pragma unroll
  for (int i = 0; i < 4; ++i) {
    int k = ty + i * 8;
    tile[k][tx] = f2b(W[(size_t)(by + k) * N + bx + tx]);
  }
  __syncthreads();
  #pragma unroll
  for (int i = 0; i < 4; ++i) {
    int n = ty + i * 8;
    WT[(size_t)(bx + n) * K + by + tx] = tile[tx][n];
  }
}

// ---------------- LayerNorm (C=1024, EPS=1e-3), bf16 out ----------------
__global__ __launch_bounds__(256)
void ln_f32_kernel(const float* __restrict__ X, const float* __restrict__ G,
                   const float* __restrict__ Bt, u16* __restrict__ O) {
  const int row = blockIdx.x;
  const int tid = threadIdx.x;
  const float* xr = X + (size_t)row * 1024;
  float4 xv = *(const float4*)(xr + tid * 4);
  float v0 = xv.x, v1 = xv.y, v2 = xv.z, v3 = xv.w;
  float s = v0 + v1 + v2 + v3;
  float q = v0 * v0 + v1 * v1 + v2 * v2 + v3 * v3;
  #pragma unroll
  for (int off = 32; off > 0; off >>= 1) {
    s += __shfl_down(s, off);
    q += __shfl_down(q, off);
  }
  __shared__ float red[8];
  int wave = tid >> 6, lane = tid & 63;
  if (lane == 0) { red[wave] = s; red[4 + wave] = q; }
  __syncthreads();
  s = red[0] + red[1] + red[2] + red[3];
  q = red[4] + red[5] + red[6] + red[7];
  float mean = s * (1.f / 1024.f);
  float var = q * (1.f / 1024.f) - mean * mean;
  float rstd = rsqrtf(var + 1e-3f);
  float4 gv = *(const float4*)(G + tid * 4);
  float4 bv = *(const float4*)(Bt + tid * 4);
  ushort4 ov;
  ov.x = f2b((v0 - mean) * rstd * gv.x + bv.x);
  ov.y = f2b((v1 - mean) * rstd * gv.y + bv.y);
  ov.z = f2b((v2 - mean) * rstd * gv.z + bv.z);
  ov.w = f2b((v3 - mean) * rstd * gv.w + bv.w);
  *(ushort4*)(O + (size_t)row * 1024 + tid * 4) = ov;
}

__global__ __launch_bounds__(256)
void ln_bf16_kernel(const u16* __restrict__ X, const float* __restrict__ G,
                    const float* __restrict__ Bt, u16* __restrict__ O) {
  const int row = blockIdx.x;
  const int tid = threadIdx.x;
  const u16* xr = X + (size_t)row * 1024;
  ushort4 xv = *(const ushort4*)(xr + tid * 4);
  float v0 = b2f(xv.x), v1 = b2f(xv.y), v2 = b2f(xv.z), v3 = b2f(xv.w);
  float s = v0 + v1 + v2 + v3;
  float q = v0 * v0 + v1 * v1 + v2 * v2 + v3 * v3;
  #pragma unroll
  for (int off = 32; off > 0; off >>= 1) {
    s += __shfl_down(s, off);
    q += __shfl_down(q, off);
  }
  __shared__ float red[8];
  int wave = tid >> 6, lane = tid & 63;
  if (lane == 0) { red[wave] = s; red[4 + wave] = q; }
  __syncthreads();
  s = red[0] + red[1] + red[2] + red[3];
  q = red[4] + red[5] + red[6] + red[7];
  float mean = s * (1.f / 1024.f);
  float var = q * (1.f / 1024.f) - mean * mean;
  float rstd = rsqrtf(var + 1e-3f);
  float4 gv = *(const float4*)(G + tid * 4);
  float4 bv = *(const float4*)(Bt + tid * 4);
  ushort4 ov;
  ov.x = f2b((v0 - mean) * rstd * gv.x + bv.x);
  ov.y = f2b((v1 - mean) * rstd * gv.y + bv.y);
  ov.z = f2b((v2 - mean) * rstd * gv.z + bv.z);
  ov.w = f2b((v3 - mean) * rstd * gv.w + bv.w);
  *(ushort4*)(O + (size_t)row * 1024 + tid * 4) = ov;
}

// ---------------- NT GEMM: A[M,K] * BT[N,K]^T, bf16 in, fp32 acc -------------
// 128x128 tile, BK=32, double-buffered ping-pong in only 32 KiB LDS:
//   [A0 | A1 | B0 | B1], each 4096 u16 (128 rows x 32 k).
// Occupancy theory (round 4): round-3's 64 KiB capped residency at 2
// blocks/CU; at 32 KiB the limit moves to the unified VGPR+AGPR file
// (~156 regs/wave -> 3 waves/SIMD) = 3 blocks/CU -> +50% TLP to hide the
// top-of-iter vmcnt wait.
// Super-row swizzle (global_load_lds needs a LINEAR dest): super-row
// sr = r>>1 (128B) holds rows 2sr,2sr+1; slot s in [0,8) stores
// (r = 2sr+(s&1), chunk c = (s>>1) ^ (sr&3)). Staged by pre-swizzling the
// per-lane GLOBAL source address; frag ds_read_b128 banks = slot*4 only
// (sr*128 = 0 mod 32 banks) -> 8 bank-quads x 2 lanes = 2-way = free.
// Per K-iter: wait vmcnt(0) (only tile t's 4 loads outstanding) + one raw
// s_barrier -> issue tile t+1's 4 loads into buffer p^1 -> 8 invariant-
// address ds_read_b128 frags -> 16 MFMA.
// EPI 0: qkv 3-part bias; 1: bias+residual (bf16 out); 2: bias+GELU(fast);
// 3: bias+residual (fp32 out).
template <int EPI>
__global__ __launch_bounds__(256)
void gemm_nt(const u16* __restrict__ A, const u16* __restrict__ BT,
             void* __restrict__ Cout,
             const float* __restrict__ bias0, const float* __restrict__ bias1,
             const float* __restrict__ bias2, const u16* __restrict__ resid,
             int M, int N, int K) {
  __shared__ __align__(16) u16 smem[16384];     // 32 KiB: A0,A1,B0,B1
  const int tid = threadIdx.x;
  const int m0 = blockIdx.y * 128;
  const int n0 = blockIdx.x * 128;
  const int wave = tid >> 6, lane = tid & 63;
  const int wm = wave & 1, wn = wave >> 1;
  const int quad = lane >> 4, l16 = lane & 15;

  f32x4 acc[4][4];
  #pragma unroll
  for (int i = 0; i < 4; ++i)
    #pragma unroll
    for (int j = 0; j < 4; ++j) acc[i][j] = (f32x4){0.f, 0.f, 0.f, 0.f};

  // ---- staging addresses (computed once; sources advance 32 u16 per iter)
  // thread tid -> dest u16 idx tid*8 (load0, sr=tid>>3) and +2048 (load1,
  // sr=tid>>3+32 -> same chunk since 32=0 mod 4, row +64).
  const int s7 = tid & 7, t8 = tid >> 3;
  const int rS = 2 * t8 + (s7 & 1);
  const int cS = ((s7 >> 1) ^ (t8 & 3)) * 8;
  const u16* aS0 = A + (size_t)(m0 + rS) * K + cS;
  const u16* aS1 = aS0 + (size_t)64 * K;
  const u16* bS0 = BT + (size_t)(n0 + rS) * K + cS;
  const u16* bS1 = bS0 + (size_t)64 * K;
  u16* aD = &smem[(u32)tid * 8];
  u16* bD = &smem[8192u + (u32)tid * 8];

  auto stage = [&](int p, int koff) {
    g2l16(aS0 + koff, aD + p * 4096);
    g2l16(aS1 + koff, aD + p * 4096 + 2048);
    g2l16(bS0 + koff, bD + p * 4096);
    g2l16(bS1 + koff, bD + p * 4096 + 2048);
  };

  // ---- fragment read bases (loop-invariant; +i*512 imm, +p*4096 toggle)
  // row = (wm|wn)*64 + i*16 + l16: sr = ..*32 + i*8 + (l16>>1),
  // slot = 2*(quad ^ ((l16>>1)&3)) + (l16&1).
  const int g = l16 >> 1, par = l16 & 1;
  const u32 slotq = (u32)(2 * (quad ^ (g & 3)) + par) * 8;
  const u32 aBase = (u32)(wm * 32 + g) * 64 + slotq;
  const u32 bBase = 8192u + (u32)(wn * 32 + g) * 64 + slotq;

  const int nt = K >> 5;
  stage(0, 0);   // prologue: tile 0 into buffer 0

  for (int t = 0; t < nt; ++t) {
    const int p = t & 1;
    // only tile t's 4 loads are outstanding here (t+1 not yet issued)
    asm volatile("s_waitcnt vmcnt(0)" ::: "memory");
    __builtin_amdgcn_s_barrier();
    if (t + 1 < nt) stage(p ^ 1, (t + 1) * 32);  // prefetch under MFMAs
    const u16* pA = &smem[aBase + (u32)p * 4096];
    const u16* pB = &smem[bBase + (u32)p * 4096];
    bf16x8 aF[4], bF[4];
    #pragma unroll
    for (int i = 0; i < 4; ++i) aF[i] = *(const bf16x8*)(pA + i * 512);
    #pragma unroll
    for (int j = 0; j < 4; ++j) bF[j] = *(const bf16x8*)(pB + j * 512);
    #pragma unroll
    for (int i = 0; i < 4; ++i)
      #pragma unroll
      for (int j = 0; j < 4; ++j)
        acc[i][j] = __builtin_amdgcn_mfma_f32_16x16x32_bf16(
            aF[i], bF[j], acc[i][j], 0, 0, 0);
  }
  __syncthreads();   // K-loop reads done before epilogue overwrites smem

  // ---- epilogue: stage 64x128 halves through LDS (16B-chunk XOR swizzle),
  // then coalesced stores. C/D layout: col=lane&15, row=quad*4+reg (m89).
  #pragma unroll
  for (int half = 0; half < 2; ++half) {
    if (wm == half) {
      #pragma unroll
      for (int i = 0; i < 4; ++i) {
        const int fsw = (i * 4 + quad) & 7;     // (lrow>>2)&7
        #pragma unroll
        for (int j = 0; j < 4; ++j) {
          const int chunk = (wn * 8 + j * 2 + (l16 >> 3)) ^ fsw;
          const int base = chunk * 8 + (l16 & 7);
          #pragma unroll
          for (int rr = 0; rr < 4; ++rr) {
            const int lrow = i * 16 + quad * 4 + rr;
            smem[lrow * 128 + base] = f2b(acc[i][j][rr]);
          }
        }
      }
    }
    __syncthreads();
    #pragma unroll
    for (int s = 0; s < 4; ++s) {
      const int lrow = s * 16 + (tid >> 4);
      const int chunk = tid & 15;
      const int fsw = (lrow >> 2) & 7;
      bf16x8 cv = *(const bf16x8*)&smem[lrow * 128 + ((chunk ^ fsw) * 8)];
      const int gr = m0 + half * 64 + lrow;
      const int gc = n0 + chunk * 8;
      const float* bp_ = bias0;
      int cb = gc;
      if (EPI == 0) {
        const int selb = gc >> 10;
        bp_ = (selb == 0) ? bias0 : ((selb == 1) ? bias1 : bias2);
        cb = gc & 1023;
      }
      float4 bv0 = *(const float4*)(bp_ + cb);
      float4 bv1 = *(const float4*)(bp_ + cb + 4);
      float vv[8];
      #pragma unroll
      for (int e = 0; e < 8; ++e) {
        float be = (e < 4) ? ((const float*)&bv0)[e] : ((const float*)&bv1)[e - 4];
        vv[e] = b2f(((const u16*)&cv)[e]) + be;
      }
      if (EPI == 2) {
        #pragma unroll
        for (int e = 0; e < 8; ++e) vv[e] = gelu_fast(vv[e]);
      }
      if (EPI == 1 || EPI == 3) {
        bf16x8 rv = *(const bf16x8*)(resid + (size_t)gr * N + gc);
        #pragma unroll
        for (int e = 0; e < 8; ++e) vv[e] += b2f(((const u16*)&rv)[e]);
      }
      if (EPI == 3) {
        float4 o0 = {vv[0], vv[1], vv[2], vv[3]};
        float4 o1 = {vv[4], vv[5], vv[6], vv[7]};
        float* op = (float*)Cout + (size_t)gr * N + gc;
        *(float4*)op = o0;
        *(float4*)(op + 4) = o1;
      } else {
        bf16x8 ov;
        #pragma unroll
        for (int e = 0; e < 8; ++e) ((u16*)&ov)[e] = f2b(vv[e]);
        *(bf16x8*)((u16*)Cout + (size_t)gr * N + gc) = ov;
      }
    }
    __syncthreads();   // half-0 reads done before half-1 overwrites
  }
}

// ---------------- attention (no softmax!): M = scale * K^T V per (b,h) -------
// Split over d2 halves (grid.y = 2). Register tile 2 d1 x 4 d2 per thread:
// inner loop reads 1x ds_read_b64 (Ks pair) + 1x ds_read_b128 (Vs quad)
// per tt instead of 9x b32 -> ~2.5x less LDS issue time.
__global__ __launch_bounds__(256)
void attn_m_kernel(const u16* __restrict__ qkv, float* __restrict__ Mbuf) {
  const int bh = blockIdx.x;
  const int half = blockIdx.y;                  // d2 cols [half*32, half*32+32)
  const int b = bh >> 4, h = bh & 15;
  const u16* Kp = qkv + (size_t)b * 1024 * 3072 + 1024 + h * 64;
  const u16* Vp = Kp + 1024 + half * 32;
  __shared__ __align__(16) float Ks[64 * 64];
  __shared__ __align__(16) float Vs[64 * 36];   // stride 36: 16B-aligned rows
  const int tid = threadIdx.x;
  const int d1p = (tid & 31) * 2, d2q = (tid >> 5) * 4;
  const int lr = tid >> 3, lc = (tid & 7) * 8;  // K staging: 32 rows x 8 cols
  const int vr = tid >> 2, vc = (tid & 3) * 8;  // V staging: 64 rows x 8 cols
  float acc[2][4];
  #pragma unroll
  for (int a = 0; a < 2; ++a)
    #pragma unroll
    for (int j = 0; j < 4; ++j) acc[a][j] = 0.f;
  for (int t0 = 0; t0 < 1024; t0 += 64) {
    __syncthreads();
    #pragma unroll
    for (int it = 0; it < 2; ++it) {
      int r = it * 32 + lr;
      const u16* ks = Kp + (size_t)(t0 + r) * 3072 + lc;
      ushort4 a0 = *(const ushort4*)ks;
      ushort4 a1 = *(const ushort4*)(ks + 4);
      float* kd = &Ks[r * 64 + lc];
      kd[0] = b2f(a0.x); kd[1] = b2f(a0.y); kd[2] = b2f(a0.z); kd[3] = b2f(a0.w);
      kd[4] = b2f(a1.x); kd[5] = b2f(a1.y); kd[6] = b2f(a1.z); kd[7] = b2f(a1.w);
    }
    {
      const u16* vs = Vp + (size_t)(t0 + vr) * 3072 + vc;
      ushort4 c0 = *(const ushort4*)vs;
      ushort4 c1 = *(const ushort4*)(vs + 4);
      float* vd = &Vs[vr * 36 + vc];
      vd[0] = b2f(c0.x); vd[1] = b2f(c0.y); vd[2] = b2f(c0.z); vd[3] = b2f(c0.w);
      vd[4] = b2f(c1.x); vd[5] = b2f(c1.y); vd[6] = b2f(c1.z); vd[7] = b2f(c1.w);
    }
    __syncthreads();
    #pragma unroll 8
    for (int tt = 0; tt < 64; ++tt) {
      float2 kv = *(const float2*)&Ks[tt * 64 + d1p];
      float4 vv = *(const float4*)&Vs[tt * 36 + d2q];
      #pragma unroll
      for (int j = 0; j < 4; ++j) {
        acc[0][j] += kv.x * ((const float*)&vv)[j];
        acc[1][j] += kv.y * ((const float*)&vv)[j];
      }
    }
  }
  #pragma unroll
  for (int a = 0; a < 2; ++a) {
    float4 o = {acc[a][0] * 0.03125f, acc[a][1] * 0.03125f,
                acc[a][2] * 0.03125f, acc[a][3] * 0.03125f};  // C^-0.5 = 1/32
    *(float4*)(Mbuf + (size_t)bh * 4096 + (d1p + a) * 64 + half * 32 + d2q) = o;
  }
}

// heads = Q @ M, written directly in concat layout cat[b,t, h*64+d]
__global__ __launch_bounds__(256)
void attn_h_kernel(const u16* __restrict__ qkv, const float* __restrict__ Mbuf,
                   u16* __restrict__ cat) {
  const int bh = blockIdx.x;
  const int tch = blockIdx.y;
  const int b = bh >> 4, h = bh & 15;
  __shared__ __align__(16) float Ms[64 * 64];
  __shared__ __align__(16) float Qs[64 * 65];
  const int tid = threadIdx.x;
  const float* Msrc = Mbuf + (size_t)bh * 4096;
  #pragma unroll
  for (int i = 0; i < 16; ++i) Ms[i * 256 + tid] = Msrc[i * 256 + tid];
  const u16* Qp = qkv + (size_t)(b * 1024 + tch * 64) * 3072 + h * 64;
  {
    const int lr = tid >> 3, lc = (tid & 7) * 8;
    #pragma unroll
    for (int it = 0; it < 2; ++it) {
      int r = it * 32 + lr;
      const u16* qs = Qp + (size_t)r * 3072 + lc;
      ushort4 a0 = *(const ushort4*)qs;
      ushort4 a1 = *(const ushort4*)(qs + 4);
      float* qd = &Qs[r * 65 + lc];
      qd[0] = b2f(a0.x); qd[1] = b2f(a0.y); qd[2] = b2f(a0.z); qd[3] = b2f(a0.w);
      qd[4] = b2f(a1.x); qd[5] = b2f(a1.y); qd[6] = b2f(a1.z); qd[7] = b2f(a1.w);
    }
  }
  __syncthreads();
  const int tl = tid >> 2, db = (tid & 3) * 16;
  float acc[16];
  #pragma unroll
  for (int j = 0; j < 16; ++j) acc[j] = 0.f;
  #pragma unroll 4
  for (int k = 0; k < 64; ++k) {
    float qv = Qs[tl * 65 + k];
    #pragma unroll
    for (int m4 = 0; m4 < 4; ++m4) {
      float4 mv = *(const float4*)&Ms[k * 64 + db + m4 * 4];
      #pragma unroll
      for (int j = 0; j < 4; ++j) acc[m4 * 4 + j] += qv * ((const float*)&mv)[j];
    }
  }
  u16* Cp = cat + (size_t)(b * 1024 + tch * 64 + tl) * 1024 + h * 64 + db;
  ushort4 o0 = {f2b(acc[0]), f2b(acc[1]), f2b(acc[2]), f2b(acc[3])};
  ushort4 o1 = {f2b(acc[4]), f2b(acc[5]), f2b(acc[6]), f2b(acc[7])};
  ushort4 o2 = {f2b(acc[8]), f2b(acc[9]), f2b(acc[10]), f2b(acc[11])};
  ushort4 o3 = {f2b(acc[12]), f2b(acc[13]), f2b(acc[14]), f2b(acc[15])};
  *(ushort4*)(Cp + 0) = o0;
  *(ushort4*)(Cp + 4) = o1;
  *(ushort4*)(Cp + 8) = o2;
  *(ushort4*)(Cp + 12) = o3;
}

extern "C" void kernel_launch(void* const* d_in, const int* in_sizes, int n_in,
                              void* d_out, int out_size, void* d_ws, size_t ws_size,
                              hipStream_t stream) {
  (void)in_sizes; (void)n_in; (void)out_size; (void)ws_size;
  const float* x     = (const float*)d_in[0];
  const float* Wq    = (const float*)d_in[1];
  const float* bq    = (const float*)d_in[2];
  const float* Wk    = (const float*)d_in[3];
  const float* bk    = (const float*)d_in[4];
  const float* Wv    = (const float*)d_in[5];
  const float* bv    = (const float*)d_in[6];
  const float* Wp    = (const float*)d_in[7];
  const float* bp    = (const float*)d_in[8];
  const float* W1    = (const float*)d_in[9];
  const float* b1    = (const float*)d_in[10];
  const float* W2    = (const float*)d_in[11];
  const float* b2    = (const float*)d_in[12];
  const float* ln1w  = (const float*)d_in[13];
  const float* ln1b  = (const float*)d_in[14];
  const float* ln2w  = (const float*)d_in[15];
  const float* ln2b  = (const float*)d_in[16];

  char* ws = (char*)d_ws;
  u16* x1    = (u16*)(ws);                        // 16 MiB  [8192,1024] bf16
  u16* qkv   = (u16*)(ws + 16777216);             // 48 MiB  [8192,3072] bf16
  u16* cat   = (u16*)(ws + 67108864);             // 16 MiB  [8192,1024] bf16
  u16* yb    = (u16*)(ws + 83886080);             // 16 MiB  [8192,1024] bf16
  u16* x2    = (u16*)(ws + 100663296);            // 16 MiB  [8192,1024] bf16
  u16* WqkvT = (u16*)(ws + 117440512);            // 6 MiB   [3072,1024] bf16
  u16* WpT   = (u16*)(ws + 123731968);            // 2 MiB   [1024,1024] bf16
  u16* W1T   = (u16*)(ws + 125829120);            // 8 MiB   [4096,1024] bf16
  u16* W2T   = (u16*)(ws + 134217728);            // 8 MiB   [1024,4096] bf16
  float* Mb  = (float*)(ws + 142606336);          // 2 MiB   [128,64,64] fp32
  u16* hb    = (u16*)(ws + 16777216);             // 64 MiB, reuses dead qkv+cat

  repack_qkv_tiled<<<dim3(16, 48), 256, 0, stream>>>(Wq, Wk, Wv, WqkvT);
  transpose_tiled<<<dim3(32, 32), 256, 0, stream>>>(Wp, WpT, 1024, 1024);
  transpose_tiled<<<dim3(128, 32), 256, 0, stream>>>(W1, W1T, 4096, 1024);
  transpose_tiled<<<dim3(32, 128), 256, 0, stream>>>(W2, W2T, 1024, 4096);

  ln_f32_kernel<<<8192, 256, 0, stream>>>(x, ln1w, ln1b, x1);

  gemm_nt<0><<<dim3(24, 64), 256, 0, stream>>>(x1, WqkvT, qkv, bq, bk, bv, nullptr,
                                               8192, 3072, 1024);
  attn_m_kernel<<<dim3(128, 2), 256, 0, stream>>>(qkv, Mb);
  attn_h_kernel<<<dim3(128, 16), 256, 0, stream>>>(qkv, Mb, cat);

  gemm_nt<1><<<dim3(8, 64), 256, 0, stream>>>(cat, WpT, yb, bp, nullptr, nullptr, x1,
                                              8192, 1024, 1024);
  ln_bf16_kernel<<<8192, 256, 0, stream>>>(yb, ln2w, ln2b, x2);

  gemm_nt<2><<<dim3(32, 64), 256, 0, stream>>>(x2, W1T, hb, b1, nullptr, nullptr, nullptr,
                                               8192, 4096, 1024);
  gemm_nt<3><<<dim3(8, 64), 256, 0, stream>>>(hb, W2T, d_out, b2, nullptr, nullptr, x2,
                                              8192, 1024, 4096);
}

// Round 5
// 482.442 us; speedup vs baseline: 1.6122x; 1.0582x over previous
//
#include <hip/hip_runtime.h>

typedef unsigned short u16;
typedef unsigned int u32;
typedef unsigned long long u64;
typedef __attribute__((ext_vector_type(8))) short bf16x8;
typedef __attribute__((ext_vector_type(4))) float f32x4;

__device__ __forceinline__ float b2f(u16 v) {
  union { u32 u; float f; } c; c.u = ((u32)v) << 16; return c.f;
}
__device__ __forceinline__ u16 f2b(float f) {
  union { float f; u32 u; } c; c.f = f;
  return (u16)((c.u + 0x7fffu + ((c.u >> 16) & 1u)) >> 16);
}

// async global->LDS, 16B per lane (global_load_lds_dwordx4).
__device__ __forceinline__ void g2l16(const u16* g, u16* l) {
  __builtin_amdgcn_global_load_lds(
      (const __attribute__((address_space(1))) u32*)g,
      (__attribute__((address_space(3))) u32*)l,
      16, 0, 0);
}

// tanh-form GELU: verified rounds 1-4 (absmax unchanged at 0.0625).
__device__ __forceinline__ float gelu_fast(float x) {
  float z2 = -1.5957691216057308f * x * (1.0f + 0.044715f * x * x);  // -2z
  z2 = fminf(fmaxf(z2, -30.f), 30.f);
  float t = __expf(z2);
  return x * __builtin_amdgcn_rcpf(1.0f + t);
}

// ---------------- LDS-tiled weight repacks (fp32 in -> bf16 out) -------------
__global__ __launch_bounds__(256)
void repack_qkv_tiled(const float* __restrict__ Wq, const float* __restrict__ Wk,
                      const float* __restrict__ Wv, u16* __restrict__ WT) {
  __shared__ u16 tile[64][65];
  const int sh = blockIdx.y, sel = sh >> 4, h = sh & 15;
  const float* W = (sel == 0) ? Wq : ((sel == 1) ? Wk : Wv);
  const int k0 = blockIdx.x * 64;
  {
    const int d = threadIdx.x & 63, r = threadIdx.x >> 6;
    #pragma unroll
    for (int i = 0; i < 16; ++i) {
      int k = r * 16 + i;
      tile[k][d] = f2b(W[(size_t)h * 65536 + (size_t)(k0 + k) * 64 + d]);
    }
  }
  __syncthreads();
  {
    const int k = threadIdx.x & 63, dd = threadIdx.x >> 6;
    #pragma unroll
    for (int i = 0; i < 16; ++i) {
      int d2 = dd * 16 + i;
      WT[((size_t)sel * 1024 + h * 64 + d2) * 1024 + k0 + k] = tile[k][d2];
    }
  }
}

__global__ __launch_bounds__(256)
void transpose_tiled(const float* __restrict__ W, u16* __restrict__ WT,
                     int N, int K) {
  __shared__ u16 tile[32][33];
  const int bx = blockIdx.x * 32;   // n
  const int by = blockIdx.y * 32;   // k
  const int tx = threadIdx.x & 31, ty = threadIdx.x >> 5;
  #pragma unroll
  for (int i = 0; i < 4; ++i) {
    int k = ty + i * 8;
    tile[k][tx] = f2b(W[(size_t)(by + k) * N + bx + tx]);
  }
  __syncthreads();
  #pragma unroll
  for (int i = 0; i < 4; ++i) {
    int n = ty + i * 8;
    WT[(size_t)(bx + n) * K + by + tx] = tile[tx][n];
  }
}

// ---------------- LayerNorm (C=1024, EPS=1e-3), bf16 out ----------------
__global__ __launch_bounds__(256)
void ln_f32_kernel(const float* __restrict__ X, const float* __restrict__ G,
                   const float* __restrict__ Bt, u16* __restrict__ O) {
  const int row = blockIdx.x;
  const int tid = threadIdx.x;
  const float* xr = X + (size_t)row * 1024;
  float4 xv = *(const float4*)(xr + tid * 4);
  float v0 = xv.x, v1 = xv.y, v2 = xv.z, v3 = xv.w;
  float s = v0 + v1 + v2 + v3;
  float q = v0 * v0 + v1 * v1 + v2 * v2 + v3 * v3;
  #pragma unroll
  for (int off = 32; off > 0; off >>= 1) {
    s += __shfl_down(s, off);
    q += __shfl_down(q, off);
  }
  __shared__ float red[8];
  int wave = tid >> 6, lane = tid & 63;
  if (lane == 0) { red[wave] = s; red[4 + wave] = q; }
  __syncthreads();
  s = red[0] + red[1] + red[2] + red[3];
  q = red[4] + red[5] + red[6] + red[7];
  float mean = s * (1.f / 1024.f);
  float var = q * (1.f / 1024.f) - mean * mean;
  float rstd = rsqrtf(var + 1e-3f);
  float4 gv = *(const float4*)(G + tid * 4);
  float4 bv = *(const float4*)(Bt + tid * 4);
  ushort4 ov;
  ov.x = f2b((v0 - mean) * rstd * gv.x + bv.x);
  ov.y = f2b((v1 - mean) * rstd * gv.y + bv.y);
  ov.z = f2b((v2 - mean) * rstd * gv.z + bv.z);
  ov.w = f2b((v3 - mean) * rstd * gv.w + bv.w);
  *(ushort4*)(O + (size_t)row * 1024 + tid * 4) = ov;
}

__global__ __launch_bounds__(256)
void ln_bf16_kernel(const u16* __restrict__ X, const float* __restrict__ G,
                    const float* __restrict__ Bt, u16* __restrict__ O) {
  const int row = blockIdx.x;
  const int tid = threadIdx.x;
  const u16* xr = X + (size_t)row * 1024;
  ushort4 xv = *(const ushort4*)(xr + tid * 4);
  float v0 = b2f(xv.x), v1 = b2f(xv.y), v2 = b2f(xv.z), v3 = b2f(xv.w);
  float s = v0 + v1 + v2 + v3;
  float q = v0 * v0 + v1 * v1 + v2 * v2 + v3 * v3;
  #pragma unroll
  for (int off = 32; off > 0; off >>= 1) {
    s += __shfl_down(s, off);
    q += __shfl_down(q, off);
  }
  __shared__ float red[8];
  int wave = tid >> 6, lane = tid & 63;
  if (lane == 0) { red[wave] = s; red[4 + wave] = q; }
  __syncthreads();
  s = red[0] + red[1] + red[2] + red[3];
  q = red[4] + red[5] + red[6] + red[7];
  float mean = s * (1.f / 1024.f);
  float var = q * (1.f / 1024.f) - mean * mean;
  float rstd = rsqrtf(var + 1e-3f);
  float4 gv = *(const float4*)(G + tid * 4);
  float4 bv = *(const float4*)(Bt + tid * 4);
  ushort4 ov;
  ov.x = f2b((v0 - mean) * rstd * gv.x + bv.x);
  ov.y = f2b((v1 - mean) * rstd * gv.y + bv.y);
  ov.z = f2b((v2 - mean) * rstd * gv.z + bv.z);
  ov.w = f2b((v3 - mean) * rstd * gv.w + bv.w);
  *(ushort4*)(O + (size_t)row * 1024 + tid * 4) = ov;
}

// ---------------- NT GEMM: A[M,K] * BT[N,K]^T, bf16 in, fp32 acc -------------
// 128x128 tile, BK=64, ping-pong double-buffered LDS (64 KiB):
//   As(p) = smem[p*8192], Bs(p) = smem[16384 + p*8192].
// Round-5 change (issue-earliest): tile t+1's 8 global_load_lds issue
// IMMEDIATELY after the top-of-iter barrier (the earliest legal point: the
// barrier proves all waves' iter t-1 fragment reads of buffer p^1 are done),
// BEFORE iter t's 16 fragment ds_reads. Lead time from issue to the next
// iteration's vmcnt(0) wait is now a full iteration (~830 cyc) instead of
// the MFMA region only (~350 cyc) -> covers L3/HBM load latency.
// At the top of iter t only tile t's 8 loads are outstanding, so vmcnt(0)
// is still an exact wait. Row = 128B in LDS; 16B k-chunk slot XOR-swizzled
// with (row&7) (T2). Epilogue reuses smem[0:16384] for the C transpose.
// EPI 0: qkv 3-part bias; 1: bias+residual (bf16 out); 2: bias+GELU(fast);
// 3: bias+residual (fp32 out).
template <int EPI>
__global__ __launch_bounds__(256)
void gemm_nt(const u16* __restrict__ A, const u16* __restrict__ BT,
             void* __restrict__ Cout,
             const float* __restrict__ bias0, const float* __restrict__ bias1,
             const float* __restrict__ bias2, const u16* __restrict__ resid,
             int M, int N, int K) {
  __shared__ __align__(16) u16 smem[32768];     // 64 KiB: A0,A1,B0,B1
  const int tid = threadIdx.x;
  const int m0 = blockIdx.y * 128;
  const int n0 = blockIdx.x * 128;
  const int wave = tid >> 6, lane = tid & 63;
  const int wm = wave & 1, wn = wave >> 1;
  const int quad = lane >> 4, l16 = lane & 15;

  f32x4 acc[4][4];
  #pragma unroll
  for (int i = 0; i < 4; ++i)
    #pragma unroll
    for (int j = 0; j < 4; ++j) acc[i][j] = (f32x4){0.f, 0.f, 0.f, 0.f};

  // staging: thread tid covers row rowS (+32,+64,+96), stored slot = tid&7.
  // Stored slot s of row r holds logical k-chunk s ^ (r&7).
  const int rowS = tid >> 3;                    // 0..31
  const int swz = ((tid & 7) ^ ((tid >> 3) & 7)) * 8;   // source k-offset
  const u16* aB = A + (size_t)(m0 + rowS) * K + swz;
  const u16* bB = BT + (size_t)(n0 + rowS) * K + swz;
  const size_t rstep = (size_t)32 * K;          // 32 rows down

  const int nt = K >> 6;

  // issue the 8 global_load_lds for K-tile kt into buffer p
  auto stage = [&](int p, int kt) {
    u16* aD = &smem[(u32)p * 8192 + (u32)tid * 8];
    u16* bD = &smem[16384u + (u32)p * 8192 + (u32)tid * 8];
    const int k0 = kt * 64;
    #pragma unroll
    for (int cc = 0; cc < 4; ++cc) {
      g2l16(aB + k0 + cc * rstep, aD + cc * 2048);
      g2l16(bB + k0 + cc * rstep, bD + cc * 2048);
    }
  };

  stage(0, 0);   // prologue: tile 0 into buffer 0

  for (int t = 0; t < nt; ++t) {
    const int p = t & 1;
    // only tile t's 8 loads are outstanding here (t+1 not yet issued)
    asm volatile("s_waitcnt vmcnt(0)" ::: "memory");
    __builtin_amdgcn_s_barrier();
    if (t + 1 < nt) stage(p ^ 1, t + 1);   // issue-earliest: full-iter lead
    const u16* As = &smem[(u32)p * 8192];
    const u16* Bs = &smem[16384u + (u32)p * 8192];

    bf16x8 aF[2][4], bF[2][4];
    #pragma unroll
    for (int ks = 0; ks < 2; ++ks) {
      // fragment row = wm*64+i*16+l16 -> row&7 = l16&7; logical chunk ks*4+quad
      const int sOff = (((ks * 4 + quad) ^ (l16 & 7)) * 8);
      #pragma unroll
      for (int i = 0; i < 4; ++i)
        aF[ks][i] = *(const bf16x8*)&As[(wm * 64 + i * 16 + l16) * 64 + sOff];
      #pragma unroll
      for (int j = 0; j < 4; ++j)
        bF[ks][j] = *(const bf16x8*)&Bs[(wn * 64 + j * 16 + l16) * 64 + sOff];
    }
    #pragma unroll
    for (int ks = 0; ks < 2; ++ks)
      #pragma unroll
      for (int i = 0; i < 4; ++i)
        #pragma unroll
        for (int j = 0; j < 4; ++j)
          acc[i][j] = __builtin_amdgcn_mfma_f32_16x16x32_bf16(
              aF[ks][i], bF[ks][j], acc[i][j], 0, 0, 0);
  }
  __syncthreads();   // K-loop reads done before epilogue overwrites smem

  // ---- epilogue: stage 64x128 halves through LDS (16B-chunk XOR swizzle),
  // then coalesced stores. C/D layout: col=lane&15, row=quad*4+reg (m89).
  #pragma unroll
  for (int half = 0; half < 2; ++half) {
    if (wm == half) {
      #pragma unroll
      for (int i = 0; i < 4; ++i) {
        const int fsw = (i * 4 + quad) & 7;     // (lrow>>2)&7
        #pragma unroll
        for (int j = 0; j < 4; ++j) {
          const int chunk = (wn * 8 + j * 2 + (l16 >> 3)) ^ fsw;
          const int base = chunk * 8 + (l16 & 7);
          #pragma unroll
          for (int rr = 0; rr < 4; ++rr) {
            const int lrow = i * 16 + quad * 4 + rr;
            smem[lrow * 128 + base] = f2b(acc[i][j][rr]);
          }
        }
      }
    }
    __syncthreads();
    #pragma unroll
    for (int s = 0; s < 4; ++s) {
      const int lrow = s * 16 + (tid >> 4);
      const int chunk = tid & 15;
      const int fsw = (lrow >> 2) & 7;
      bf16x8 cv = *(const bf16x8*)&smem[lrow * 128 + ((chunk ^ fsw) * 8)];
      const int gr = m0 + half * 64 + lrow;
      const int gc = n0 + chunk * 8;
      const float* bp_ = bias0;
      int cb = gc;
      if (EPI == 0) {
        const int selb = gc >> 10;
        bp_ = (selb == 0) ? bias0 : ((selb == 1) ? bias1 : bias2);
        cb = gc & 1023;
      }
      float4 bv0 = *(const float4*)(bp_ + cb);
      float4 bv1 = *(const float4*)(bp_ + cb + 4);
      float vv[8];
      #pragma unroll
      for (int e = 0; e < 8; ++e) {
        float be = (e < 4) ? ((const float*)&bv0)[e] : ((const float*)&bv1)[e - 4];
        vv[e] = b2f(((const u16*)&cv)[e]) + be;
      }
      if (EPI == 2) {
        #pragma unroll
        for (int e = 0; e < 8; ++e) vv[e] = gelu_fast(vv[e]);
      }
      if (EPI == 1 || EPI == 3) {
        bf16x8 rv = *(const bf16x8*)(resid + (size_t)gr * N + gc);
        #pragma unroll
        for (int e = 0; e < 8; ++e) vv[e] += b2f(((const u16*)&rv)[e]);
      }
      if (EPI == 3) {
        float4 o0 = {vv[0], vv[1], vv[2], vv[3]};
        float4 o1 = {vv[4], vv[5], vv[6], vv[7]};
        float* op = (float*)Cout + (size_t)gr * N + gc;
        *(float4*)op = o0;
        *(float4*)(op + 4) = o1;
      } else {
        bf16x8 ov;
        #pragma unroll
        for (int e = 0; e < 8; ++e) ((u16*)&ov)[e] = f2b(vv[e]);
        *(bf16x8*)((u16*)Cout + (size_t)gr * N + gc) = ov;
      }
    }
    __syncthreads();   // half-0 reads done before half-1 overwrites
  }
}

// ---------------- attention (no softmax!): M = scale * K^T V per (b,h) -------
// Split over d2 halves (grid.y = 2). Register tile 2 d1 x 4 d2 per thread:
// inner loop reads 1x ds_read_b64 (Ks pair) + 1x ds_read_b128 (Vs quad)
// per tt instead of 9x b32 (round-4 win, kept).
__global__ __launch_bounds__(256)
void attn_m_kernel(const u16* __restrict__ qkv, float* __restrict__ Mbuf) {
  const int bh = blockIdx.x;
  const int half = blockIdx.y;                  // d2 cols [half*32, half*32+32)
  const int b = bh >> 4, h = bh & 15;
  const u16* Kp = qkv + (size_t)b * 1024 * 3072 + 1024 + h * 64;
  const u16* Vp = Kp + 1024 + half * 32;
  __shared__ __align__(16) float Ks[64 * 64];
  __shared__ __align__(16) float Vs[64 * 36];   // stride 36: 16B-aligned rows
  const int tid = threadIdx.x;
  const int d1p = (tid & 31) * 2, d2q = (tid >> 5) * 4;
  const int lr = tid >> 3, lc = (tid & 7) * 8;  // K staging: 32 rows x 8 cols
  const int vr = tid >> 2, vc = (tid & 3) * 8;  // V staging: 64 rows x 8 cols
  float acc[2][4];
  #pragma unroll
  for (int a = 0; a < 2; ++a)
    #pragma unroll
    for (int j = 0; j < 4; ++j) acc[a][j] = 0.f;
  for (int t0 = 0; t0 < 1024; t0 += 64) {
    __syncthreads();
    #pragma unroll
    for (int it = 0; it < 2; ++it) {
      int r = it * 32 + lr;
      const u16* ks = Kp + (size_t)(t0 + r) * 3072 + lc;
      ushort4 a0 = *(const ushort4*)ks;
      ushort4 a1 = *(const ushort4*)(ks + 4);
      float* kd = &Ks[r * 64 + lc];
      kd[0] = b2f(a0.x); kd[1] = b2f(a0.y); kd[2] = b2f(a0.z); kd[3] = b2f(a0.w);
      kd[4] = b2f(a1.x); kd[5] = b2f(a1.y); kd[6] = b2f(a1.z); kd[7] = b2f(a1.w);
    }
    {
      const u16* vs = Vp + (size_t)(t0 + vr) * 3072 + vc;
      ushort4 c0 = *(const ushort4*)vs;
      ushort4 c1 = *(const ushort4*)(vs + 4);
      float* vd = &Vs[vr * 36 + vc];
      vd[0] = b2f(c0.x); vd[1] = b2f(c0.y); vd[2] = b2f(c0.z); vd[3] = b2f(c0.w);
      vd[4] = b2f(c1.x); vd[5] = b2f(c1.y); vd[6] = b2f(c1.z); vd[7] = b2f(c1.w);
    }
    __syncthreads();
    #pragma unroll 8
    for (int tt = 0; tt < 64; ++tt) {
      float2 kv = *(const float2*)&Ks[tt * 64 + d1p];
      float4 vv = *(const float4*)&Vs[tt * 36 + d2q];
      #pragma unroll
      for (int j = 0; j < 4; ++j) {
        acc[0][j] += kv.x * ((const float*)&vv)[j];
        acc[1][j] += kv.y * ((const float*)&vv)[j];
      }
    }
  }
  #pragma unroll
  for (int a = 0; a < 2; ++a) {
    float4 o = {acc[a][0] * 0.03125f, acc[a][1] * 0.03125f,
                acc[a][2] * 0.03125f, acc[a][3] * 0.03125f};  // C^-0.5 = 1/32
    *(float4*)(Mbuf + (size_t)bh * 4096 + (d1p + a) * 64 + half * 32 + d2q) = o;
  }
}

// heads = Q @ M, written directly in concat layout cat[b,t, h*64+d]
__global__ __launch_bounds__(256)
void attn_h_kernel(const u16* __restrict__ qkv, const float* __restrict__ Mbuf,
                   u16* __restrict__ cat) {
  const int bh = blockIdx.x;
  const int tch = blockIdx.y;
  const int b = bh >> 4, h = bh & 15;
  __shared__ __align__(16) float Ms[64 * 64];
  __shared__ __align__(16) float Qs[64 * 65];
  const int tid = threadIdx.x;
  const float* Msrc = Mbuf + (size_t)bh * 4096;
  #pragma unroll
  for (int i = 0; i < 16; ++i) Ms[i * 256 + tid] = Msrc[i * 256 + tid];
  const u16* Qp = qkv + (size_t)(b * 1024 + tch * 64) * 3072 + h * 64;
  {
    const int lr = tid >> 3, lc = (tid & 7) * 8;
    #pragma unroll
    for (int it = 0; it < 2; ++it) {
      int r = it * 32 + lr;
      const u16* qs = Qp + (size_t)r * 3072 + lc;
      ushort4 a0 = *(const ushort4*)qs;
      ushort4 a1 = *(const ushort4*)(qs + 4);
      float* qd = &Qs[r * 65 + lc];
      qd[0] = b2f(a0.x); qd[1] = b2f(a0.y); qd[2] = b2f(a0.z); qd[3] = b2f(a0.w);
      qd[4] = b2f(a1.x); qd[5] = b2f(a1.y); qd[6] = b2f(a1.z); qd[7] = b2f(a1.w);
    }
  }
  __syncthreads();
  const int tl = tid >> 2, db = (tid & 3) * 16;
  float acc[16];
  #pragma unroll
  for (int j = 0; j < 16; ++j) acc[j] = 0.f;
  #pragma unroll 4
  for (int k = 0; k < 64; ++k) {
    float qv = Qs[tl * 65 + k];
    #pragma unroll
    for (int m4 = 0; m4 < 4; ++m4) {
      float4 mv = *(const float4*)&Ms[k * 64 + db + m4 * 4];
      #pragma unroll
      for (int j = 0; j < 4; ++j) acc[m4 * 4 + j] += qv * ((const float*)&mv)[j];
    }
  }
  u16* Cp = cat + (size_t)(b * 1024 + tch * 64 + tl) * 1024 + h * 64 + db;
  ushort4 o0 = {f2b(acc[0]), f2b(acc[1]), f2b(acc[2]), f2b(acc[3])};
  ushort4 o1 = {f2b(acc[4]), f2b(acc[5]), f2b(acc[6]), f2b(acc[7])};
  ushort4 o2 = {f2b(acc[8]), f2b(acc[9]), f2b(acc[10]), f2b(acc[11])};
  ushort4 o3 = {f2b(acc[12]), f2b(acc[13]), f2b(acc[14]), f2b(acc[15])};
  *(ushort4*)(Cp + 0) = o0;
  *(ushort4*)(Cp + 4) = o1;
  *(ushort4*)(Cp + 8) = o2;
  *(ushort4*)(Cp + 12) = o3;
}

extern "C" void kernel_launch(void* const* d_in, const int* in_sizes, int n_in,
                              void* d_out, int out_size, void* d_ws, size_t ws_size,
                              hipStream_t stream) {
  (void)in_sizes; (void)n_in; (void)out_size; (void)ws_size;
  const float* x     = (const float*)d_in[0];
  const float* Wq    = (const float*)d_in[1];
  const float* bq    = (const float*)d_in[2];
  const float* Wk    = (const float*)d_in[3];
  const float* bk    = (const float*)d_in[4];
  const float* Wv    = (const float*)d_in[5];
  const float* bv    = (const float*)d_in[6];
  const float* Wp    = (const float*)d_in[7];
  const float* bp    = (const float*)d_in[8];
  const float* W1    = (const float*)d_in[9];
  const float* b1    = (const float*)d_in[10];
  const float* W2    = (const float*)d_in[11];
  const float* b2    = (const float*)d_in[12];
  const float* ln1w  = (const float*)d_in[13];
  const float* ln1b  = (const float*)d_in[14];
  const float* ln2w  = (const float*)d_in[15];
  const float* ln2b  = (const float*)d_in[16];

  char* ws = (char*)d_ws;
  u16* x1    = (u16*)(ws);                        // 16 MiB  [8192,1024] bf16
  u16* qkv   = (u16*)(ws + 16777216);             // 48 MiB  [8192,3072] bf16
  u16* cat   = (u16*)(ws + 67108864);             // 16 MiB  [8192,1024] bf16
  u16* yb    = (u16*)(ws + 83886080);             // 16 MiB  [8192,1024] bf16
  u16* x2    = (u16*)(ws + 100663296);            // 16 MiB  [8192,1024] bf16
  u16* WqkvT = (u16*)(ws + 117440512);            // 6 MiB   [3072,1024] bf16
  u16* WpT   = (u16*)(ws + 123731968);            // 2 MiB   [1024,1024] bf16
  u16* W1T   = (u16*)(ws + 125829120);            // 8 MiB   [4096,1024] bf16
  u16* W2T   = (u16*)(ws + 134217728);            // 8 MiB   [1024,4096] bf16
  float* Mb  = (float*)(ws + 142606336);          // 2 MiB   [128,64,64] fp32
  u16* hb    = (u16*)(ws + 16777216);             // 64 MiB, reuses dead qkv+cat

  repack_qkv_tiled<<<dim3(16, 48), 256, 0, stream>>>(Wq, Wk, Wv, WqkvT);
  transpose_tiled<<<dim3(32, 32), 256, 0, stream>>>(Wp, WpT, 1024, 1024);
  transpose_tiled<<<dim3(128, 32), 256, 0, stream>>>(W1, W1T, 4096, 1024);
  transpose_tiled<<<dim3(32, 128), 256, 0, stream>>>(W2, W2T, 1024, 4096);

  ln_f32_kernel<<<8192, 256, 0, stream>>>(x, ln1w, ln1b, x1);

  gemm_nt<0><<<dim3(24, 64), 256, 0, stream>>>(x1, WqkvT, qkv, bq, bk, bv, nullptr,
                                               8192, 3072, 1024);
  attn_m_kernel<<<dim3(128, 2), 256, 0, stream>>>(qkv, Mb);
  attn_h_kernel<<<dim3(128, 16), 256, 0, stream>>>(qkv, Mb, cat);

  gemm_nt<1><<<dim3(8, 64), 256, 0, stream>>>(cat, WpT, yb, bp, nullptr, nullptr, x1,
                                              8192, 1024, 1024);
  ln_bf16_kernel<<<8192, 256, 0, stream>>>(yb, ln2w, ln2b, x2);

  gemm_nt<2><<<dim3(32, 64), 256, 0, stream>>>(x2, W1T, hb, b1, nullptr, nullptr, nullptr,
                                               8192, 4096, 1024);
  gemm_nt<3><<<dim3(8, 64), 256, 0, stream>>>(hb, W2T, d_out, b2, nullptr, nullptr, x2,
                                              8192, 1024, 4096);
}

// Round 6
// 481.758 us; speedup vs baseline: 1.6145x; 1.0014x over previous
//
#include <hip/hip_runtime.h>

typedef unsigned short u16;
typedef unsigned int u32;
typedef unsigned long long u64;
typedef __attribute__((ext_vector_type(8))) short bf16x8;
typedef __attribute__((ext_vector_type(4))) float f32x4;

__device__ __forceinline__ float b2f(u16 v) {
  union { u32 u; float f; } c; c.u = ((u32)v) << 16; return c.f;
}
__device__ __forceinline__ u16 f2b(float f) {
  union { float f; u32 u; } c; c.f = f;
  return (u16)((c.u + 0x7fffu + ((c.u >> 16) & 1u)) >> 16);
}

// async global->LDS, 16B per lane (global_load_lds_dwordx4).
__device__ __forceinline__ void g2l16(const u16* g, u16* l) {
  __builtin_amdgcn_global_load_lds(
      (const __attribute__((address_space(1))) u32*)g,
      (__attribute__((address_space(3))) u32*)l,
      16, 0, 0);
}

// tanh-form GELU: verified rounds 1-5 (absmax unchanged at 0.0625).
__device__ __forceinline__ float gelu_fast(float x) {
  float z2 = -1.5957691216057308f * x * (1.0f + 0.044715f * x * x);  // -2z
  z2 = fminf(fmaxf(z2, -30.f), 30.f);
  float t = __expf(z2);
  return x * __builtin_amdgcn_rcpf(1.0f + t);
}

// ---------------- LDS-tiled weight repacks (fp32 in -> bf16 out) -------------
__global__ __launch_bounds__(256)
void repack_qkv_tiled(const float* __restrict__ Wq, const float* __restrict__ Wk,
                      const float* __restrict__ Wv, u16* __restrict__ WT) {
  __shared__ u16 tile[64][65];
  const int sh = blockIdx.y, sel = sh >> 4, h = sh & 15;
  const float* W = (sel == 0) ? Wq : ((sel == 1) ? Wk : Wv);
  const int k0 = blockIdx.x * 64;
  {
    const int d = threadIdx.x & 63, r = threadIdx.x >> 6;
    #pragma unroll
    for (int i = 0; i < 16; ++i) {
      int k = r * 16 + i;
      tile[k][d] = f2b(W[(size_t)h * 65536 + (size_t)(k0 + k) * 64 + d]);
    }
  }
  __syncthreads();
  {
    const int k = threadIdx.x & 63, dd = threadIdx.x >> 6;
    #pragma unroll
    for (int i = 0; i < 16; ++i) {
      int d2 = dd * 16 + i;
      WT[((size_t)sel * 1024 + h * 64 + d2) * 1024 + k0 + k] = tile[k][d2];
    }
  }
}

__global__ __launch_bounds__(256)
void transpose_tiled(const float* __restrict__ W, u16* __restrict__ WT,
                     int N, int K) {
  __shared__ u16 tile[32][33];
  const int bx = blockIdx.x * 32;   // n
  const int by = blockIdx.y * 32;   // k
  const int tx = threadIdx.x & 31, ty = threadIdx.x >> 5;
  #pragma unroll
  for (int i = 0; i < 4; ++i) {
    int k = ty + i * 8;
    tile[k][tx] = f2b(W[(size_t)(by + k) * N + bx + tx]);
  }
  __syncthreads();
  #pragma unroll
  for (int i = 0; i < 4; ++i) {
    int n = ty + i * 8;
    WT[(size_t)(bx + n) * K + by + tx] = tile[tx][n];
  }
}

// ---------------- LayerNorm (C=1024, EPS=1e-3), bf16 out ----------------
__global__ __launch_bounds__(256)
void ln_f32_kernel(const float* __restrict__ X, const float* __restrict__ G,
                   const float* __restrict__ Bt, u16* __restrict__ O) {
  const int row = blockIdx.x;
  const int tid = threadIdx.x;
  const float* xr = X + (size_t)row * 1024;
  float4 xv = *(const float4*)(xr + tid * 4);
  float v0 = xv.x, v1 = xv.y, v2 = xv.z, v3 = xv.w;
  float s = v0 + v1 + v2 + v3;
  float q = v0 * v0 + v1 * v1 + v2 * v2 + v3 * v3;
  #pragma unroll
  for (int off = 32; off > 0; off >>= 1) {
    s += __shfl_down(s, off);
    q += __shfl_down(q, off);
  }
  __shared__ float red[8];
  int wave = tid >> 6, lane = tid & 63;
  if (lane == 0) { red[wave] = s; red[4 + wave] = q; }
  __syncthreads();
  s = red[0] + red[1] + red[2] + red[3];
  q = red[4] + red[5] + red[6] + red[7];
  float mean = s * (1.f / 1024.f);
  float var = q * (1.f / 1024.f) - mean * mean;
  float rstd = rsqrtf(var + 1e-3f);
  float4 gv = *(const float4*)(G + tid * 4);
  float4 bv = *(const float4*)(Bt + tid * 4);
  ushort4 ov;
  ov.x = f2b((v0 - mean) * rstd * gv.x + bv.x);
  ov.y = f2b((v1 - mean) * rstd * gv.y + bv.y);
  ov.z = f2b((v2 - mean) * rstd * gv.z + bv.z);
  ov.w = f2b((v3 - mean) * rstd * gv.w + bv.w);
  *(ushort4*)(O + (size_t)row * 1024 + tid * 4) = ov;
}

__global__ __launch_bounds__(256)
void ln_bf16_kernel(const u16* __restrict__ X, const float* __restrict__ G,
                    const float* __restrict__ Bt, u16* __restrict__ O) {
  const int row = blockIdx.x;
  const int tid = threadIdx.x;
  const u16* xr = X + (size_t)row * 1024;
  ushort4 xv = *(const ushort4*)(xr + tid * 4);
  float v0 = b2f(xv.x), v1 = b2f(xv.y), v2 = b2f(xv.z), v3 = b2f(xv.w);
  float s = v0 + v1 + v2 + v3;
  float q = v0 * v0 + v1 * v1 + v2 * v2 + v3 * v3;
  #pragma unroll
  for (int off = 32; off > 0; off >>= 1) {
    s += __shfl_down(s, off);
    q += __shfl_down(q, off);
  }
  __shared__ float red[8];
  int wave = tid >> 6, lane = tid & 63;
  if (lane == 0) { red[wave] = s; red[4 + wave] = q; }
  __syncthreads();
  s = red[0] + red[1] + red[2] + red[3];
  q = red[4] + red[5] + red[6] + red[7];
  float mean = s * (1.f / 1024.f);
  float var = q * (1.f / 1024.f) - mean * mean;
  float rstd = rsqrtf(var + 1e-3f);
  float4 gv = *(const float4*)(G + tid * 4);
  float4 bv = *(const float4*)(Bt + tid * 4);
  ushort4 ov;
  ov.x = f2b((v0 - mean) * rstd * gv.x + bv.x);
  ov.y = f2b((v1 - mean) * rstd * gv.y + bv.y);
  ov.z = f2b((v2 - mean) * rstd * gv.z + bv.z);
  ov.w = f2b((v3 - mean) * rstd * gv.w + bv.w);
  *(ushort4*)(O + (size_t)row * 1024 + tid * 4) = ov;
}

// ---------------- NT GEMM: A[M,K] * BT[N,K]^T, bf16 in, fp32 acc -------------
// 128x128 tile, BK=64, ping-pong double-buffered LDS (64 KiB):
//   As(p) = smem[p*8192], Bs(p) = smem[16384 + p*8192].
// Round-6: PROVEN round-3 ordering restored. Per K-iter:
//   wait vmcnt(0) (exactly tile t's 8 loads outstanding) + one raw s_barrier
//   -> 16 fragment ds_read_b128 (clean LDS pipe; these gate the MFMAs)
//   -> issue tile t+1's 8 global_load_lds into buffer p^1 (returns land
//      during the MFMA region, off the critical path)
//   -> 32 MFMA.
// R5 (stage before frag reads) measured WORSE (95.5 vs 88.4 us): staging
// return traffic + issue slots collide with the fragment reads that gate
// MFMA start. Safety: the top-of-iter barrier orders all waves' iter t-1
// fragment reads before buffer p^1 is overwritten; each wave executes the
// counted wait before the barrier, so post-barrier all staged data is valid.
// Row = 128B in LDS; 16B k-chunk slot XOR-swizzled with (row&7) (T2).
// Epilogue reuses smem[0:16384] for the C transpose.
// EPI 0: qkv 3-part bias; 1: bias+residual (bf16 out); 2: bias+GELU(fast);
// 3: bias+residual (fp32 out).
template <int EPI>
__global__ __launch_bounds__(256)
void gemm_nt(const u16* __restrict__ A, const u16* __restrict__ BT,
             void* __restrict__ Cout,
             const float* __restrict__ bias0, const float* __restrict__ bias1,
             const float* __restrict__ bias2, const u16* __restrict__ resid,
             int M, int N, int K) {
  __shared__ __align__(16) u16 smem[32768];     // 64 KiB: A0,A1,B0,B1
  const int tid = threadIdx.x;
  const int m0 = blockIdx.y * 128;
  const int n0 = blockIdx.x * 128;
  const int wave = tid >> 6, lane = tid & 63;
  const int wm = wave & 1, wn = wave >> 1;
  const int quad = lane >> 4, l16 = lane & 15;

  f32x4 acc[4][4];
  #pragma unroll
  for (int i = 0; i < 4; ++i)
    #pragma unroll
    for (int j = 0; j < 4; ++j) acc[i][j] = (f32x4){0.f, 0.f, 0.f, 0.f};

  // staging: thread tid covers row rowS (+32,+64,+96), stored slot = tid&7.
  // Stored slot s of row r holds logical k-chunk s ^ (r&7).
  const int rowS = tid >> 3;                    // 0..31
  const int swz = ((tid & 7) ^ ((tid >> 3) & 7)) * 8;   // source k-offset
  const u16* aB = A + (size_t)(m0 + rowS) * K + swz;
  const u16* bB = BT + (size_t)(n0 + rowS) * K + swz;
  const size_t rstep = (size_t)32 * K;          // 32 rows down

  const int nt = K >> 6;

  // issue the 8 global_load_lds for K-tile kt into buffer p
  auto stage = [&](int p, int kt) {
    u16* aD = &smem[(u32)p * 8192 + (u32)tid * 8];
    u16* bD = &smem[16384u + (u32)p * 8192 + (u32)tid * 8];
    const int k0 = kt * 64;
    #pragma unroll
    for (int cc = 0; cc < 4; ++cc) {
      g2l16(aB + k0 + cc * rstep, aD + cc * 2048);
      g2l16(bB + k0 + cc * rstep, bD + cc * 2048);
    }
  };

  stage(0, 0);   // prologue: tile 0 into buffer 0

  for (int t = 0; t < nt; ++t) {
    const int p = t & 1;
    // only tile t's 8 loads are outstanding here (t+1 not yet issued)
    asm volatile("s_waitcnt vmcnt(0)" ::: "memory");
    __builtin_amdgcn_s_barrier();
    const u16* As = &smem[(u32)p * 8192];
    const u16* Bs = &smem[16384u + (u32)p * 8192];

    bf16x8 aF[2][4], bF[2][4];
    #pragma unroll
    for (int ks = 0; ks < 2; ++ks) {
      // fragment row = wm*64+i*16+l16 -> row&7 = l16&7; logical chunk ks*4+quad
      const int sOff = (((ks * 4 + quad) ^ (l16 & 7)) * 8);
      #pragma unroll
      for (int i = 0; i < 4; ++i)
        aF[ks][i] = *(const bf16x8*)&As[(wm * 64 + i * 16 + l16) * 64 + sOff];
      #pragma unroll
      for (int j = 0; j < 4; ++j)
        bF[ks][j] = *(const bf16x8*)&Bs[(wn * 64 + j * 16 + l16) * 64 + sOff];
    }
    if (t + 1 < nt) stage(p ^ 1, t + 1);   // prefetch flies under the MFMAs
    #pragma unroll
    for (int ks = 0; ks < 2; ++ks)
      #pragma unroll
      for (int i = 0; i < 4; ++i)
        #pragma unroll
        for (int j = 0; j < 4; ++j)
          acc[i][j] = __builtin_amdgcn_mfma_f32_16x16x32_bf16(
              aF[ks][i], bF[ks][j], acc[i][j], 0, 0, 0);
  }
  __syncthreads();   // K-loop reads done before epilogue overwrites smem

  // ---- epilogue: stage 64x128 halves through LDS (16B-chunk XOR swizzle),
  // then coalesced stores. C/D layout: col=lane&15, row=quad*4+reg (m89).
  #pragma unroll
  for (int half = 0; half < 2; ++half) {
    if (wm == half) {
      #pragma unroll
      for (int i = 0; i < 4; ++i) {
        const int fsw = (i * 4 + quad) & 7;     // (lrow>>2)&7
        #pragma unroll
        for (int j = 0; j < 4; ++j) {
          const int chunk = (wn * 8 + j * 2 + (l16 >> 3)) ^ fsw;
          const int base = chunk * 8 + (l16 & 7);
          #pragma unroll
          for (int rr = 0; rr < 4; ++rr) {
            const int lrow = i * 16 + quad * 4 + rr;
            smem[lrow * 128 + base] = f2b(acc[i][j][rr]);
          }
        }
      }
    }
    __syncthreads();
    #pragma unroll
    for (int s = 0; s < 4; ++s) {
      const int lrow = s * 16 + (tid >> 4);
      const int chunk = tid & 15;
      const int fsw = (lrow >> 2) & 7;
      bf16x8 cv = *(const bf16x8*)&smem[lrow * 128 + ((chunk ^ fsw) * 8)];
      const int gr = m0 + half * 64 + lrow;
      const int gc = n0 + chunk * 8;
      const float* bp_ = bias0;
      int cb = gc;
      if (EPI == 0) {
        const int selb = gc >> 10;
        bp_ = (selb == 0) ? bias0 : ((selb == 1) ? bias1 : bias2);
        cb = gc & 1023;
      }
      float4 bv0 = *(const float4*)(bp_ + cb);
      float4 bv1 = *(const float4*)(bp_ + cb + 4);
      float vv[8];
      #pragma unroll
      for (int e = 0; e < 8; ++e) {
        float be = (e < 4) ? ((const float*)&bv0)[e] : ((const float*)&bv1)[e - 4];
        vv[e] = b2f(((const u16*)&cv)[e]) + be;
      }
      if (EPI == 2) {
        #pragma unroll
        for (int e = 0; e < 8; ++e) vv[e] = gelu_fast(vv[e]);
      }
      if (EPI == 1 || EPI == 3) {
        bf16x8 rv = *(const bf16x8*)(resid + (size_t)gr * N + gc);
        #pragma unroll
        for (int e = 0; e < 8; ++e) vv[e] += b2f(((const u16*)&rv)[e]);
      }
      if (EPI == 3) {
        float4 o0 = {vv[0], vv[1], vv[2], vv[3]};
        float4 o1 = {vv[4], vv[5], vv[6], vv[7]};
        float* op = (float*)Cout + (size_t)gr * N + gc;
        *(float4*)op = o0;
        *(float4*)(op + 4) = o1;
      } else {
        bf16x8 ov;
        #pragma unroll
        for (int e = 0; e < 8; ++e) ((u16*)&ov)[e] = f2b(vv[e]);
        *(bf16x8*)((u16*)Cout + (size_t)gr * N + gc) = ov;
      }
    }
    __syncthreads();   // half-0 reads done before half-1 overwrites
  }
}

// ---------------- attention (no softmax!): M = scale * K^T V per (b,h) -------
// Split over d2 halves (grid.y = 2). Register tile 2 d1 x 4 d2 per thread:
// inner loop reads 1x ds_read_b64 (Ks pair) + 1x ds_read_b128 (Vs quad)
// per tt instead of 9x b32 (round-4 win, kept).
__global__ __launch_bounds__(256)
void attn_m_kernel(const u16* __restrict__ qkv, float* __restrict__ Mbuf) {
  const int bh = blockIdx.x;
  const int half = blockIdx.y;                  // d2 cols [half*32, half*32+32)
  const int b = bh >> 4, h = bh & 15;
  const u16* Kp = qkv + (size_t)b * 1024 * 3072 + 1024 + h * 64;
  const u16* Vp = Kp + 1024 + half * 32;
  __shared__ __align__(16) float Ks[64 * 64];
  __shared__ __align__(16) float Vs[64 * 36];   // stride 36: 16B-aligned rows
  const int tid = threadIdx.x;
  const int d1p = (tid & 31) * 2, d2q = (tid >> 5) * 4;
  const int lr = tid >> 3, lc = (tid & 7) * 8;  // K staging: 32 rows x 8 cols
  const int vr = tid >> 2, vc = (tid & 3) * 8;  // V staging: 64 rows x 8 cols
  float acc[2][4];
  #pragma unroll
  for (int a = 0; a < 2; ++a)
    #pragma unroll
    for (int j = 0; j < 4; ++j) acc[a][j] = 0.f;
  for (int t0 = 0; t0 < 1024; t0 += 64) {
    __syncthreads();
    #pragma unroll
    for (int it = 0; it < 2; ++it) {
      int r = it * 32 + lr;
      const u16* ks = Kp + (size_t)(t0 + r) * 3072 + lc;
      ushort4 a0 = *(const ushort4*)ks;
      ushort4 a1 = *(const ushort4*)(ks + 4);
      float* kd = &Ks[r * 64 + lc];
      kd[0] = b2f(a0.x); kd[1] = b2f(a0.y); kd[2] = b2f(a0.z); kd[3] = b2f(a0.w);
      kd[4] = b2f(a1.x); kd[5] = b2f(a1.y); kd[6] = b2f(a1.z); kd[7] = b2f(a1.w);
    }
    {
      const u16* vs = Vp + (size_t)(t0 + vr) * 3072 + vc;
      ushort4 c0 = *(const ushort4*)vs;
      ushort4 c1 = *(const ushort4*)(vs + 4);
      float* vd = &Vs[vr * 36 + vc];
      vd[0] = b2f(c0.x); vd[1] = b2f(c0.y); vd[2] = b2f(c0.z); vd[3] = b2f(c0.w);
      vd[4] = b2f(c1.x); vd[5] = b2f(c1.y); vd[6] = b2f(c1.z); vd[7] = b2f(c1.w);
    }
    __syncthreads();
    #pragma unroll 8
    for (int tt = 0; tt < 64; ++tt) {
      float2 kv = *(const float2*)&Ks[tt * 64 + d1p];
      float4 vv = *(const float4*)&Vs[tt * 36 + d2q];
      #pragma unroll
      for (int j = 0; j < 4; ++j) {
        acc[0][j] += kv.x * ((const float*)&vv)[j];
        acc[1][j] += kv.y * ((const float*)&vv)[j];
      }
    }
  }
  #pragma unroll
  for (int a = 0; a < 2; ++a) {
    float4 o = {acc[a][0] * 0.03125f, acc[a][1] * 0.03125f,
                acc[a][2] * 0.03125f, acc[a][3] * 0.03125f};  // C^-0.5 = 1/32
    *(float4*)(Mbuf + (size_t)bh * 4096 + (d1p + a) * 64 + half * 32 + d2q) = o;
  }
}

// heads = Q @ M, written directly in concat layout cat[b,t, h*64+d]
__global__ __launch_bounds__(256)
void attn_h_kernel(const u16* __restrict__ qkv, const float* __restrict__ Mbuf,
                   u16* __restrict__ cat) {
  const int bh = blockIdx.x;
  const int tch = blockIdx.y;
  const int b = bh >> 4, h = bh & 15;
  __shared__ __align__(16) float Ms[64 * 64];
  __shared__ __align__(16) float Qs[64 * 65];
  const int tid = threadIdx.x;
  const float* Msrc = Mbuf + (size_t)bh * 4096;
  #pragma unroll
  for (int i = 0; i < 16; ++i) Ms[i * 256 + tid] = Msrc[i * 256 + tid];
  const u16* Qp = qkv + (size_t)(b * 1024 + tch * 64) * 3072 + h * 64;
  {
    const int lr = tid >> 3, lc = (tid & 7) * 8;
    #pragma unroll
    for (int it = 0; it < 2; ++it) {
      int r = it * 32 + lr;
      const u16* qs = Qp + (size_t)r * 3072 + lc;
      ushort4 a0 = *(const ushort4*)qs;
      ushort4 a1 = *(const ushort4*)(qs + 4);
      float* qd = &Qs[r * 65 + lc];
      qd[0] = b2f(a0.x); qd[1] = b2f(a0.y); qd[2] = b2f(a0.z); qd[3] = b2f(a0.w);
      qd[4] = b2f(a1.x); qd[5] = b2f(a1.y); qd[6] = b2f(a1.z); qd[7] = b2f(a1.w);
    }
  }
  __syncthreads();
  const int tl = tid >> 2, db = (tid & 3) * 16;
  float acc[16];
  #pragma unroll
  for (int j = 0; j < 16; ++j) acc[j] = 0.f;
  #pragma unroll 4
  for (int k = 0; k < 64; ++k) {
    float qv = Qs[tl * 65 + k];
    #pragma unroll
    for (int m4 = 0; m4 < 4; ++m4) {
      float4 mv = *(const float4*)&Ms[k * 64 + db + m4 * 4];
      #pragma unroll
      for (int j = 0; j < 4; ++j) acc[m4 * 4 + j] += qv * ((const float*)&mv)[j];
    }
  }
  u16* Cp = cat + (size_t)(b * 1024 + tch * 64 + tl) * 1024 + h * 64 + db;
  ushort4 o0 = {f2b(acc[0]), f2b(acc[1]), f2b(acc[2]), f2b(acc[3])};
  ushort4 o1 = {f2b(acc[4]), f2b(acc[5]), f2b(acc[6]), f2b(acc[7])};
  ushort4 o2 = {f2b(acc[8]), f2b(acc[9]), f2b(acc[10]), f2b(acc[11])};
  ushort4 o3 = {f2b(acc[12]), f2b(acc[13]), f2b(acc[14]), f2b(acc[15])};
  *(ushort4*)(Cp + 0) = o0;
  *(ushort4*)(Cp + 4) = o1;
  *(ushort4*)(Cp + 8) = o2;
  *(ushort4*)(Cp + 12) = o3;
}

extern "C" void kernel_launch(void* const* d_in, const int* in_sizes, int n_in,
                              void* d_out, int out_size, void* d_ws, size_t ws_size,
                              hipStream_t stream) {
  (void)in_sizes; (void)n_in; (void)out_size; (void)ws_size;
  const float* x     = (const float*)d_in[0];
  const float* Wq    = (const float*)d_in[1];
  const float* bq    = (const float*)d_in[2];
  const float* Wk    = (const float*)d_in[3];
  const float* bk    = (const float*)d_in[4];
  const float* Wv    = (const float*)d_in[5];
  const float* bv    = (const float*)d_in[6];
  const float* Wp    = (const float*)d_in[7];
  const float* bp    = (const float*)d_in[8];
  const float* W1    = (const float*)d_in[9];
  const float* b1    = (const float*)d_in[10];
  const float* W2    = (const float*)d_in[11];
  const float* b2    = (const float*)d_in[12];
  const float* ln1w  = (const float*)d_in[13];
  const float* ln1b  = (const float*)d_in[14];
  const float* ln2w  = (const float*)d_in[15];
  const float* ln2b  = (const float*)d_in[16];

  char* ws = (char*)d_ws;
  u16* x1    = (u16*)(ws);                        // 16 MiB  [8192,1024] bf16
  u16* qkv   = (u16*)(ws + 16777216);             // 48 MiB  [8192,3072] bf16
  u16* cat   = (u16*)(ws + 67108864);             // 16 MiB  [8192,1024] bf16
  u16* yb    = (u16*)(ws + 83886080);             // 16 MiB  [8192,1024] bf16
  u16* x2    = (u16*)(ws + 100663296);            // 16 MiB  [8192,1024] bf16
  u16* WqkvT = (u16*)(ws + 117440512);            // 6 MiB   [3072,1024] bf16
  u16* WpT   = (u16*)(ws + 123731968);            // 2 MiB   [1024,1024] bf16
  u16* W1T   = (u16*)(ws + 125829120);            // 8 MiB   [4096,1024] bf16
  u16* W2T   = (u16*)(ws + 134217728);            // 8 MiB   [1024,4096] bf16
  float* Mb  = (float*)(ws + 142606336);          // 2 MiB   [128,64,64] fp32
  u16* hb    = (u16*)(ws + 16777216);             // 64 MiB, reuses dead qkv+cat

  repack_qkv_tiled<<<dim3(16, 48), 256, 0, stream>>>(Wq, Wk, Wv, WqkvT);
  transpose_tiled<<<dim3(32, 32), 256, 0, stream>>>(Wp, WpT, 1024, 1024);
  transpose_tiled<<<dim3(128, 32), 256, 0, stream>>>(W1, W1T, 4096, 1024);
  transpose_tiled<<<dim3(32, 128), 256, 0, stream>>>(W2, W2T, 1024, 4096);

  ln_f32_kernel<<<8192, 256, 0, stream>>>(x, ln1w, ln1b, x1);

  gemm_nt<0><<<dim3(24, 64), 256, 0, stream>>>(x1, WqkvT, qkv, bq, bk, bv, nullptr,
                                               8192, 3072, 1024);
  attn_m_kernel<<<dim3(128, 2), 256, 0, stream>>>(qkv, Mb);
  attn_h_kernel<<<dim3(128, 16), 256, 0, stream>>>(qkv, Mb, cat);

  gemm_nt<1><<<dim3(8, 64), 256, 0, stream>>>(cat, WpT, yb, bp, nullptr, nullptr, x1,
                                              8192, 1024, 1024);
  ln_bf16_kernel<<<8192, 256, 0, stream>>>(yb, ln2w, ln2b, x2);

  gemm_nt<2><<<dim3(32, 64), 256, 0, stream>>>(x2, W1T, hb, b1, nullptr, nullptr, nullptr,
                                               8192, 4096, 1024);
  gemm_nt<3><<<dim3(8, 64), 256, 0, stream>>>(hb, W2T, d_out, b2, nullptr, nullptr, x2,
                                              8192, 1024, 4096);
}

// Round 7
// 458.698 us; speedup vs baseline: 1.6957x; 1.0503x over previous
//
#include <hip/hip_runtime.h>

typedef unsigned short u16;
typedef unsigned int u32;
typedef unsigned long long u64;
typedef __attribute__((ext_vector_type(8))) short bf16x8;
typedef __attribute__((ext_vector_type(4))) float f32x4;

__device__ __forceinline__ float b2f(u16 v) {
  union { u32 u; float f; } c; c.u = ((u32)v) << 16; return c.f;
}
__device__ __forceinline__ u16 f2b(float f) {
  union { float f; u32 u; } c; c.f = f;
  return (u16)((c.u + 0x7fffu + ((c.u >> 16) & 1u)) >> 16);
}

// async global->LDS, 16B per lane (global_load_lds_dwordx4).
__device__ __forceinline__ void g2l16(const u16* g, u16* l) {
  __builtin_amdgcn_global_load_lds(
      (const __attribute__((address_space(1))) u32*)g,
      (__attribute__((address_space(3))) u32*)l,
      16, 0, 0);
}

// tanh-form GELU: verified rounds 1-6 (absmax unchanged at 0.0625).
__device__ __forceinline__ float gelu_fast(float x) {
  float z2 = -1.5957691216057308f * x * (1.0f + 0.044715f * x * x);  // -2z
  z2 = fminf(fmaxf(z2, -30.f), 30.f);
  float t = __expf(z2);
  return x * __builtin_amdgcn_rcpf(1.0f + t);
}

// ---------------- LDS-tiled weight repacks (fp32 in -> bf16 out) -------------
__global__ __launch_bounds__(256)
void repack_qkv_tiled(const float* __restrict__ Wq, const float* __restrict__ Wk,
                      const float* __restrict__ Wv, u16* __restrict__ WT) {
  __shared__ u16 tile[64][65];
  const int sh = blockIdx.y, sel = sh >> 4, h = sh & 15;
  const float* W = (sel == 0) ? Wq : ((sel == 1) ? Wk : Wv);
  const int k0 = blockIdx.x * 64;
  {
    const int d = threadIdx.x & 63, r = threadIdx.x >> 6;
    #pragma unroll
    for (int i = 0; i < 16; ++i) {
      int k = r * 16 + i;
      tile[k][d] = f2b(W[(size_t)h * 65536 + (size_t)(k0 + k) * 64 + d]);
    }
  }
  __syncthreads();
  {
    const int k = threadIdx.x & 63, dd = threadIdx.x >> 6;
    #pragma unroll
    for (int i = 0; i < 16; ++i) {
      int d2 = dd * 16 + i;
      WT[((size_t)sel * 1024 + h * 64 + d2) * 1024 + k0 + k] = tile[k][d2];
    }
  }
}

__global__ __launch_bounds__(256)
void transpose_tiled(const float* __restrict__ W, u16* __restrict__ WT,
                     int N, int K) {
  __shared__ u16 tile[32][33];
  const int bx = blockIdx.x * 32;   // n
  const int by = blockIdx.y * 32;   // k
  const int tx = threadIdx.x & 31, ty = threadIdx.x >> 5;
  #pragma unroll
  for (int i = 0; i < 4; ++i) {
    int k = ty + i * 8;
    tile[k][tx] = f2b(W[(size_t)(by + k) * N + bx + tx]);
  }
  __syncthreads();
  #pragma unroll
  for (int i = 0; i < 4; ++i) {
    int n = ty + i * 8;
    WT[(size_t)(bx + n) * K + by + tx] = tile[tx][n];
  }
}

// ---------------- LayerNorm (C=1024, EPS=1e-3), bf16 out ----------------
__global__ __launch_bounds__(256)
void ln_f32_kernel(const float* __restrict__ X, const float* __restrict__ G,
                   const float* __restrict__ Bt, u16* __restrict__ O) {
  const int row = blockIdx.x;
  const int tid = threadIdx.x;
  const float* xr = X + (size_t)row * 1024;
  float4 xv = *(const float4*)(xr + tid * 4);
  float v0 = xv.x, v1 = xv.y, v2 = xv.z, v3 = xv.w;
  float s = v0 + v1 + v2 + v3;
  float q = v0 * v0 + v1 * v1 + v2 * v2 + v3 * v3;
  #pragma unroll
  for (int off = 32; off > 0; off >>= 1) {
    s += __shfl_down(s, off);
    q += __shfl_down(q, off);
  }
  __shared__ float red[8];
  int wave = tid >> 6, lane = tid & 63;
  if (lane == 0) { red[wave] = s; red[4 + wave] = q; }
  __syncthreads();
  s = red[0] + red[1] + red[2] + red[3];
  q = red[4] + red[5] + red[6] + red[7];
  float mean = s * (1.f / 1024.f);
  float var = q * (1.f / 1024.f) - mean * mean;
  float rstd = rsqrtf(var + 1e-3f);
  float4 gv = *(const float4*)(G + tid * 4);
  float4 bv = *(const float4*)(Bt + tid * 4);
  ushort4 ov;
  ov.x = f2b((v0 - mean) * rstd * gv.x + bv.x);
  ov.y = f2b((v1 - mean) * rstd * gv.y + bv.y);
  ov.z = f2b((v2 - mean) * rstd * gv.z + bv.z);
  ov.w = f2b((v3 - mean) * rstd * gv.w + bv.w);
  *(ushort4*)(O + (size_t)row * 1024 + tid * 4) = ov;
}

__global__ __launch_bounds__(256)
void ln_bf16_kernel(const u16* __restrict__ X, const float* __restrict__ G,
                    const float* __restrict__ Bt, u16* __restrict__ O) {
  const int row = blockIdx.x;
  const int tid = threadIdx.x;
  const u16* xr = X + (size_t)row * 1024;
  ushort4 xv = *(const ushort4*)(xr + tid * 4);
  float v0 = b2f(xv.x), v1 = b2f(xv.y), v2 = b2f(xv.z), v3 = b2f(xv.w);
  float s = v0 + v1 + v2 + v3;
  float q = v0 * v0 + v1 * v1 + v2 * v2 + v3 * v3;
  #pragma unroll
  for (int off = 32; off > 0; off >>= 1) {
    s += __shfl_down(s, off);
    q += __shfl_down(q, off);
  }
  __shared__ float red[8];
  int wave = tid >> 6, lane = tid & 63;
  if (lane == 0) { red[wave] = s; red[4 + wave] = q; }
  __syncthreads();
  s = red[0] + red[1] + red[2] + red[3];
  q = red[4] + red[5] + red[6] + red[7];
  float mean = s * (1.f / 1024.f);
  float var = q * (1.f / 1024.f) - mean * mean;
  float rstd = rsqrtf(var + 1e-3f);
  float4 gv = *(const float4*)(G + tid * 4);
  float4 bv = *(const float4*)(Bt + tid * 4);
  ushort4 ov;
  ov.x = f2b((v0 - mean) * rstd * gv.x + bv.x);
  ov.y = f2b((v1 - mean) * rstd * gv.y + bv.y);
  ov.z = f2b((v2 - mean) * rstd * gv.z + bv.z);
  ov.w = f2b((v3 - mean) * rstd * gv.w + bv.w);
  *(ushort4*)(O + (size_t)row * 1024 + tid * 4) = ov;
}

// ---------------- NT GEMM: A[M,K] * BT[N,K]^T, bf16 in, fp32 acc -------------
// 128x128 tile, BK=64, ping-pong double-buffered LDS (64 KiB), proven R3/R6
// K-loop: wait vmcnt(0) + one raw s_barrier -> 16 frag ds_read_b128 ->
// issue tile t+1's 8 global_load_lds -> 32 MFMA.
// Round-7: REGION-MAPPED XCD SWIZZLE (1-D grid). Consecutive blockIdx
// round-robin across the 8 XCDs (each with a private 4 MiB L2), so with the
// old dim3 row-major mapping the gx blocks sharing an A-panel landed on gx
// DIFFERENT XCDs -> every XCD refetched every panel. New mapping: xcd=bid&7
// owns one compact RAxRB-tile region (RA*RB = nb/8), walked row-major by
// s=bid>>3. Co-resident same-XCD blocks now share A-panels (RB sharers) and
// B-panels -> panel k-slices hit in one L2 instead of missing to L3/HBM at
// the vmcnt wait. Bijective for our grids (host passes RA,RB,NRn; NRm*NRn=8).
// EPI 0: qkv 3-part bias; 1: bias+residual (bf16 out); 2: bias+GELU(fast);
// 3: bias+residual (fp32 out).
template <int EPI>
__global__ __launch_bounds__(256)
void gemm_nt(const u16* __restrict__ A, const u16* __restrict__ BT,
             void* __restrict__ Cout,
             const float* __restrict__ bias0, const float* __restrict__ bias1,
             const float* __restrict__ bias2, const u16* __restrict__ resid,
             int M, int N, int K, int RA, int RB, int NRn) {
  __shared__ __align__(16) u16 smem[32768];     // 64 KiB: A0,A1,B0,B1
  const int tid = threadIdx.x;

  // region-mapped XCD swizzle
  const int xcd = blockIdx.x & 7;
  const int s_ = blockIdx.x >> 3;
  const int rm = xcd / NRn, rn = xcd - rm * NRn;
  const int lm = s_ / RB, ln = s_ - lm * RB;
  const int m0 = (rm * RA + lm) * 128;
  const int n0 = (rn * RB + ln) * 128;

  const int wave = tid >> 6, lane = tid & 63;
  const int wm = wave & 1, wn = wave >> 1;
  const int quad = lane >> 4, l16 = lane & 15;

  f32x4 acc[4][4];
  #pragma unroll
  for (int i = 0; i < 4; ++i)
    #pragma unroll
    for (int j = 0; j < 4; ++j) acc[i][j] = (f32x4){0.f, 0.f, 0.f, 0.f};

  // staging: thread tid covers row rowS (+32,+64,+96), stored slot = tid&7.
  // Stored slot s of row r holds logical k-chunk s ^ (r&7).
  const int rowS = tid >> 3;                    // 0..31
  const int swz = ((tid & 7) ^ ((tid >> 3) & 7)) * 8;   // source k-offset
  const u16* aB = A + (size_t)(m0 + rowS) * K + swz;
  const u16* bB = BT + (size_t)(n0 + rowS) * K + swz;
  const size_t rstep = (size_t)32 * K;          // 32 rows down

  const int nt = K >> 6;

  // issue the 8 global_load_lds for K-tile kt into buffer p
  auto stage = [&](int p, int kt) {
    u16* aD = &smem[(u32)p * 8192 + (u32)tid * 8];
    u16* bD = &smem[16384u + (u32)p * 8192 + (u32)tid * 8];
    const int k0 = kt * 64;
    #pragma unroll
    for (int cc = 0; cc < 4; ++cc) {
      g2l16(aB + k0 + cc * rstep, aD + cc * 2048);
      g2l16(bB + k0 + cc * rstep, bD + cc * 2048);
    }
  };

  stage(0, 0);   // prologue: tile 0 into buffer 0

  for (int t = 0; t < nt; ++t) {
    const int p = t & 1;
    // only tile t's 8 loads are outstanding here (t+1 not yet issued)
    asm volatile("s_waitcnt vmcnt(0)" ::: "memory");
    __builtin_amdgcn_s_barrier();
    const u16* As = &smem[(u32)p * 8192];
    const u16* Bs = &smem[16384u + (u32)p * 8192];

    bf16x8 aF[2][4], bF[2][4];
    #pragma unroll
    for (int ks = 0; ks < 2; ++ks) {
      // fragment row = wm*64+i*16+l16 -> row&7 = l16&7; logical chunk ks*4+quad
      const int sOff = (((ks * 4 + quad) ^ (l16 & 7)) * 8);
      #pragma unroll
      for (int i = 0; i < 4; ++i)
        aF[ks][i] = *(const bf16x8*)&As[(wm * 64 + i * 16 + l16) * 64 + sOff];
      #pragma unroll
      for (int j = 0; j < 4; ++j)
        bF[ks][j] = *(const bf16x8*)&Bs[(wn * 64 + j * 16 + l16) * 64 + sOff];
    }
    if (t + 1 < nt) stage(p ^ 1, t + 1);   // prefetch flies under the MFMAs
    #pragma unroll
    for (int ks = 0; ks < 2; ++ks)
      #pragma unroll
      for (int i = 0; i < 4; ++i)
        #pragma unroll
        for (int j = 0; j < 4; ++j)
          acc[i][j] = __builtin_amdgcn_mfma_f32_16x16x32_bf16(
              aF[ks][i], bF[ks][j], acc[i][j], 0, 0, 0);
  }
  __syncthreads();   // K-loop reads done before epilogue overwrites smem

  // ---- epilogue: stage 64x128 halves through LDS (16B-chunk XOR swizzle),
  // then coalesced stores. C/D layout: col=lane&15, row=quad*4+reg (m89).
  #pragma unroll
  for (int half = 0; half < 2; ++half) {
    if (wm == half) {
      #pragma unroll
      for (int i = 0; i < 4; ++i) {
        const int fsw = (i * 4 + quad) & 7;     // (lrow>>2)&7
        #pragma unroll
        for (int j = 0; j < 4; ++j) {
          const int chunk = (wn * 8 + j * 2 + (l16 >> 3)) ^ fsw;
          const int base = chunk * 8 + (l16 & 7);
          #pragma unroll
          for (int rr = 0; rr < 4; ++rr) {
            const int lrow = i * 16 + quad * 4 + rr;
            smem[lrow * 128 + base] = f2b(acc[i][j][rr]);
          }
        }
      }
    }
    __syncthreads();
    #pragma unroll
    for (int s = 0; s < 4; ++s) {
      const int lrow = s * 16 + (tid >> 4);
      const int chunk = tid & 15;
      const int fsw = (lrow >> 2) & 7;
      bf16x8 cv = *(const bf16x8*)&smem[lrow * 128 + ((chunk ^ fsw) * 8)];
      const int gr = m0 + half * 64 + lrow;
      const int gc = n0 + chunk * 8;
      const float* bp_ = bias0;
      int cb = gc;
      if (EPI == 0) {
        const int selb = gc >> 10;
        bp_ = (selb == 0) ? bias0 : ((selb == 1) ? bias1 : bias2);
        cb = gc & 1023;
      }
      float4 bv0 = *(const float4*)(bp_ + cb);
      float4 bv1 = *(const float4*)(bp_ + cb + 4);
      float vv[8];
      #pragma unroll
      for (int e = 0; e < 8; ++e) {
        float be = (e < 4) ? ((const float*)&bv0)[e] : ((const float*)&bv1)[e - 4];
        vv[e] = b2f(((const u16*)&cv)[e]) + be;
      }
      if (EPI == 2) {
        #pragma unroll
        for (int e = 0; e < 8; ++e) vv[e] = gelu_fast(vv[e]);
      }
      if (EPI == 1 || EPI == 3) {
        bf16x8 rv = *(const bf16x8*)(resid + (size_t)gr * N + gc);
        #pragma unroll
        for (int e = 0; e < 8; ++e) vv[e] += b2f(((const u16*)&rv)[e]);
      }
      if (EPI == 3) {
        float4 o0 = {vv[0], vv[1], vv[2], vv[3]};
        float4 o1 = {vv[4], vv[5], vv[6], vv[7]};
        float* op = (float*)Cout + (size_t)gr * N + gc;
        *(float4*)op = o0;
        *(float4*)(op + 4) = o1;
      } else {
        bf16x8 ov;
        #pragma unroll
        for (int e = 0; e < 8; ++e) ((u16*)&ov)[e] = f2b(vv[e]);
        *(bf16x8*)((u16*)Cout + (size_t)gr * N + gc) = ov;
      }
    }
    __syncthreads();   // half-0 reads done before half-1 overwrites
  }
}

// ---------------- attention (no softmax!): M = scale * K^T V per (b,h) -------
// Round-7: d2 split into 4 quarters (grid.y = 4) -> 512 blocks = 2/CU (was
// 1/CU latency-exposed). Per thread: 1 d1 x 4 d2; Vs quarter-tile 64x16
// (pad 20). Ks read = consecutive lanes (2-way, free); Vs read = wave-uniform
// broadcast (free).
__global__ __launch_bounds__(256)
void attn_m_kernel(const u16* __restrict__ qkv, float* __restrict__ Mbuf) {
  const int bh = blockIdx.x;
  const int qtr = blockIdx.y;                   // d2 cols [qtr*16, qtr*16+16)
  const int b = bh >> 4, h = bh & 15;
  const u16* Kp = qkv + (size_t)b * 1024 * 3072 + 1024 + h * 64;
  const u16* Vp = Kp + 1024 + qtr * 16;
  __shared__ __align__(16) float Ks[64 * 64];
  __shared__ __align__(16) float Vs[64 * 20];   // stride 20: 16B-aligned rows
  const int tid = threadIdx.x;
  const int d1 = tid & 63, d2q = (tid >> 6) * 4;
  const int lr = tid >> 3, lc = (tid & 7) * 8;  // K staging: 32 rows x 8 cols
  const int vr = tid >> 2, vc = (tid & 3) * 4;  // V staging: 64 rows x 4 cols
  float acc[4];
  #pragma unroll
  for (int j = 0; j < 4; ++j) acc[j] = 0.f;
  for (int t0 = 0; t0 < 1024; t0 += 64) {
    __syncthreads();
    #pragma unroll
    for (int it = 0; it < 2; ++it) {
      int r = it * 32 + lr;
      const u16* ks = Kp + (size_t)(t0 + r) * 3072 + lc;
      ushort4 a0 = *(const ushort4*)ks;
      ushort4 a1 = *(const ushort4*)(ks + 4);
      float* kd = &Ks[r * 64 + lc];
      kd[0] = b2f(a0.x); kd[1] = b2f(a0.y); kd[2] = b2f(a0.z); kd[3] = b2f(a0.w);
      kd[4] = b2f(a1.x); kd[5] = b2f(a1.y); kd[6] = b2f(a1.z); kd[7] = b2f(a1.w);
    }
    {
      const u16* vs = Vp + (size_t)(t0 + vr) * 3072 + vc;
      ushort4 c0 = *(const ushort4*)vs;
      float4 vvw = {b2f(c0.x), b2f(c0.y), b2f(c0.z), b2f(c0.w)};
      *(float4*)&Vs[vr * 20 + vc] = vvw;
    }
    __syncthreads();
    #pragma unroll 8
    for (int tt = 0; tt < 64; ++tt) {
      float kv = Ks[tt * 64 + d1];
      float4 vv = *(const float4*)&Vs[tt * 20 + d2q];
      #pragma unroll
      for (int j = 0; j < 4; ++j) acc[j] += kv * ((const float*)&vv)[j];
    }
  }
  float4 o = {acc[0] * 0.03125f, acc[1] * 0.03125f,
              acc[2] * 0.03125f, acc[3] * 0.03125f};   // C^-0.5 = 1/32
  *(float4*)(Mbuf + (size_t)bh * 4096 + d1 * 64 + qtr * 16 + d2q) = o;
}

// heads = Q @ M, written directly in concat layout cat[b,t, h*64+d]
__global__ __launch_bounds__(256)
void attn_h_kernel(const u16* __restrict__ qkv, const float* __restrict__ Mbuf,
                   u16* __restrict__ cat) {
  const int bh = blockIdx.x;
  const int tch = blockIdx.y;
  const int b = bh >> 4, h = bh & 15;
  __shared__ __align__(16) float Ms[64 * 64];
  __shared__ __align__(16) float Qs[64 * 65];
  const int tid = threadIdx.x;
  const float* Msrc = Mbuf + (size_t)bh * 4096;
  #pragma unroll
  for (int i = 0; i < 16; ++i) Ms[i * 256 + tid] = Msrc[i * 256 + tid];
  const u16* Qp = qkv + (size_t)(b * 1024 + tch * 64) * 3072 + h * 64;
  {
    const int lr = tid >> 3, lc = (tid & 7) * 8;
    #pragma unroll
    for (int it = 0; it < 2; ++it) {
      int r = it * 32 + lr;
      const u16* qs = Qp + (size_t)r * 3072 + lc;
      ushort4 a0 = *(const ushort4*)qs;
      ushort4 a1 = *(const ushort4*)(qs + 4);
      float* qd = &Qs[r * 65 + lc];
      qd[0] = b2f(a0.x); qd[1] = b2f(a0.y); qd[2] = b2f(a0.z); qd[3] = b2f(a0.w);
      qd[4] = b2f(a1.x); qd[5] = b2f(a1.y); qd[6] = b2f(a1.z); qd[7] = b2f(a1.w);
    }
  }
  __syncthreads();
  const int tl = tid >> 2, db = (tid & 3) * 16;
  float acc[16];
  #pragma unroll
  for (int j = 0; j < 16; ++j) acc[j] = 0.f;
  #pragma unroll 4
  for (int k = 0; k < 64; ++k) {
    float qv = Qs[tl * 65 + k];
    #pragma unroll
    for (int m4 = 0; m4 < 4; ++m4) {
      float4 mv = *(const float4*)&Ms[k * 64 + db + m4 * 4];
      #pragma unroll
      for (int j = 0; j < 4; ++j) acc[m4 * 4 + j] += qv * ((const float*)&mv)[j];
    }
  }
  u16* Cp = cat + (size_t)(b * 1024 + tch * 64 + tl) * 1024 + h * 64 + db;
  ushort4 o0 = {f2b(acc[0]), f2b(acc[1]), f2b(acc[2]), f2b(acc[3])};
  ushort4 o1 = {f2b(acc[4]), f2b(acc[5]), f2b(acc[6]), f2b(acc[7])};
  ushort4 o2 = {f2b(acc[8]), f2b(acc[9]), f2b(acc[10]), f2b(acc[11])};
  ushort4 o3 = {f2b(acc[12]), f2b(acc[13]), f2b(acc[14]), f2b(acc[15])};
  *(ushort4*)(Cp + 0) = o0;
  *(ushort4*)(Cp + 4) = o1;
  *(ushort4*)(Cp + 8) = o2;
  *(ushort4*)(Cp + 12) = o3;
}

extern "C" void kernel_launch(void* const* d_in, const int* in_sizes, int n_in,
                              void* d_out, int out_size, void* d_ws, size_t ws_size,
                              hipStream_t stream) {
  (void)in_sizes; (void)n_in; (void)out_size; (void)ws_size;
  const float* x     = (const float*)d_in[0];
  const float* Wq    = (const float*)d_in[1];
  const float* bq    = (const float*)d_in[2];
  const float* Wk    = (const float*)d_in[3];
  const float* bk    = (const float*)d_in[4];
  const float* Wv    = (const float*)d_in[5];
  const float* bv    = (const float*)d_in[6];
  const float* Wp    = (const float*)d_in[7];
  const float* bp    = (const float*)d_in[8];
  const float* W1    = (const float*)d_in[9];
  const float* b1    = (const float*)d_in[10];
  const float* W2    = (const float*)d_in[11];
  const float* b2    = (const float*)d_in[12];
  const float* ln1w  = (const float*)d_in[13];
  const float* ln1b  = (const float*)d_in[14];
  const float* ln2w  = (const float*)d_in[15];
  const float* ln2b  = (const float*)d_in[16];

  char* ws = (char*)d_ws;
  u16* x1    = (u16*)(ws);                        // 16 MiB  [8192,1024] bf16
  u16* qkv   = (u16*)(ws + 16777216);             // 48 MiB  [8192,3072] bf16
  u16* cat   = (u16*)(ws + 67108864);             // 16 MiB  [8192,1024] bf16
  u16* yb    = (u16*)(ws + 83886080);             // 16 MiB  [8192,1024] bf16
  u16* x2    = (u16*)(ws + 100663296);            // 16 MiB  [8192,1024] bf16
  u16* WqkvT = (u16*)(ws + 117440512);            // 6 MiB   [3072,1024] bf16
  u16* WpT   = (u16*)(ws + 123731968);            // 2 MiB   [1024,1024] bf16
  u16* W1T   = (u16*)(ws + 125829120);            // 8 MiB   [4096,1024] bf16
  u16* W2T   = (u16*)(ws + 134217728);            // 8 MiB   [1024,4096] bf16
  float* Mb  = (float*)(ws + 142606336);          // 2 MiB   [128,64,64] fp32
  u16* hb    = (u16*)(ws + 16777216);             // 64 MiB, reuses dead qkv+cat

  repack_qkv_tiled<<<dim3(16, 48), 256, 0, stream>>>(Wq, Wk, Wv, WqkvT);
  transpose_tiled<<<dim3(32, 32), 256, 0, stream>>>(Wp, WpT, 1024, 1024);
  transpose_tiled<<<dim3(128, 32), 256, 0, stream>>>(W1, W1T, 4096, 1024);
  transpose_tiled<<<dim3(32, 128), 256, 0, stream>>>(W2, W2T, 1024, 4096);

  ln_f32_kernel<<<8192, 256, 0, stream>>>(x, ln1w, ln1b, x1);

  // 1-D grids; region-mapped XCD swizzle (RA x RB tile region per XCD,
  // NRm x NRn region layout with NRm*NRn = 8; RA*RB = gridDim/8):
  // QKV : 64x24 tiles -> regions 16x12, layout 4x2
  gemm_nt<0><<<1536, 256, 0, stream>>>(x1, WqkvT, qkv, bq, bk, bv, nullptr,
                                       8192, 3072, 1024, 16, 12, 2);
  attn_m_kernel<<<dim3(128, 4), 256, 0, stream>>>(qkv, Mb);
  attn_h_kernel<<<dim3(128, 16), 256, 0, stream>>>(qkv, Mb, cat);

  // proj : 64x8 tiles -> regions 8x8, layout 8x1
  gemm_nt<1><<<512, 256, 0, stream>>>(cat, WpT, yb, bp, nullptr, nullptr, x1,
                                      8192, 1024, 1024, 8, 8, 1);
  ln_bf16_kernel<<<8192, 256, 0, stream>>>(yb, ln2w, ln2b, x2);

  // FF1 : 64x32 tiles -> regions 16x16, layout 4x2
  gemm_nt<2><<<2048, 256, 0, stream>>>(x2, W1T, hb, b1, nullptr, nullptr, nullptr,
                                       8192, 4096, 1024, 16, 16, 2);
  // FF2 : 64x8 tiles -> regions 8x8, layout 8x1
  gemm_nt<3><<<512, 256, 0, stream>>>(hb, W2T, d_out, b2, nullptr, nullptr, x2,
                                      8192, 1024, 4096, 8, 8, 1);
}